// Round 16
// baseline (560.149 us; speedup 1.0000x reference)
//
#include <hip/hip_runtime.h>
#include <stdint.h>

typedef unsigned short u16;
typedef __attribute__((ext_vector_type(8))) short short8;
typedef __attribute__((ext_vector_type(4))) float f32x4;
typedef __attribute__((ext_vector_type(16))) float f32x16;

#define NCTX 4096
#define NTGT 2048
#define DMODEL 1024
#define NH 16
#define HD 64

typedef const __attribute__((address_space(1))) uint32_t g_u32;
typedef __attribute__((address_space(3))) uint32_t lds_u32;

__device__ inline u16 f2b(float f) {
  unsigned r;
  asm("v_cvt_pk_bf16_f32 %0, %1, %1" : "=v"(r) : "v"(f));
  return (u16)r;
}
__device__ inline uint32_t pk2(float lo, float hi_) {
  uint32_t r;
  asm("v_cvt_pk_bf16_f32 %0, %1, %2" : "=v"(r) : "v"(lo), "v"(hi_));
  return r;
}
__device__ inline short8 ld8f(const float* p) {  // 8 f32 -> short8 bf16
  float4 f0 = *(const float4*)p;
  float4 f1 = *(const float4*)(p + 4);
  union { short8 s; uint32_t u[4]; } t;
  t.u[0] = pk2(f0.x, f0.y); t.u[1] = pk2(f0.z, f0.w);
  t.u[2] = pk2(f1.x, f1.y); t.u[3] = pk2(f1.z, f1.w);
  return t.s;
}

// ---------------- generic C = A * B^T  (f32 or bf16 in, f32 accum) ----------------
// AF/BF: 1 = f32 input (converted inline at load), 0 = bf16.
// MODE 1: K-writer; Ck is pre-scaled by beta*log2e (used only for scores).
template<int MODE, int AF, int BF>
__global__ __launch_bounds__(256) void gemm_bt(
    const void* __restrict__ Av, const void* __restrict__ Bv,
    float* __restrict__ Cf, u16* __restrict__ Ck, u16* __restrict__ Ckt,
    int M, int N, int Kd) {
  const int bm = blockIdx.x % (M >> 6);
  const int bn = blockIdx.x / (M >> 6);
  const int w = threadIdx.x >> 6, l = threadIdx.x & 63;
  const int lg = l >> 4, lm = l & 15;
  const int m0 = (bm << 6) + (w << 4);
  const int n0 = bn << 6;

  f32x4 acc[4] = {};

  for (int kd = 0; kd < Kd; kd += 64) {
    short8 a0, a1;
    if (AF) {
      const float* Ar = (const float*)Av + (size_t)(m0 + lm) * Kd + kd;
      a0 = ld8f(Ar + lg * 8);
      a1 = ld8f(Ar + 32 + lg * 8);
    } else {
      const u16* Ar = (const u16*)Av + (size_t)(m0 + lm) * Kd + kd;
      a0 = *(const short8*)(Ar + lg * 8);
      a1 = *(const short8*)(Ar + 32 + lg * 8);
    }
#pragma unroll
    for (int nf = 0; nf < 4; ++nf) {
      short8 b0, b1;
      if (BF) {
        const float* Br = (const float*)Bv + (size_t)(n0 + nf * 16 + lm) * Kd + kd + lg * 8;
        b0 = ld8f(Br);
        b1 = ld8f(Br + 32);
      } else {
        const u16* Br = (const u16*)Bv + (size_t)(n0 + nf * 16 + lm) * Kd + kd + lg * 8;
        b0 = *(const short8*)(Br);
        b1 = *(const short8*)(Br + 32);
      }
      acc[nf] = __builtin_amdgcn_mfma_f32_16x16x32_bf16(a0, b0, acc[nf], 0, 0, 0);
      acc[nf] = __builtin_amdgcn_mfma_f32_16x16x32_bf16(a1, b1, acc[nf], 0, 0, 0);
    }
  }

  if (MODE == 0) {
#pragma unroll
    for (int nf = 0; nf < 4; ++nf)
#pragma unroll
      for (int r = 0; r < 4; ++r)
        Cf[(size_t)(m0 + lg * 4 + r) * N + (n0 + nf * 16 + lm)] = acc[nf][r];
  } else {
    const float BL2E = 0.125f * 1.44269504088896340736f;
#pragma unroll
    for (int nf = 0; nf < 4; ++nf) {
      int n = n0 + nf * 16 + lm;
      int h = n >> 6, z = n & 63;
#pragma unroll
      for (int r = 0; r < 4; ++r) {
        int k = m0 + lg * 4 + r;
        Ck[((size_t)h * NCTX + k) * HD + z] = f2b(acc[nf][r] * BL2E);
        Ckt[((size_t)h * HD + z) * NCTX + k] = f2b(acc[nf][r]);
      }
    }
  }
}

// ---------------- 5-step energy attention, 8-wave / 128-k tiles ----------------
// 512 blocks = 16 heads x 32 q-tiles of 64 rows; 512 threads = 8 waves
// (kq 0-3 x qh 0-1). Staged tile: K 128x64 + Kt 64x128, double-buffered (64KB).
// Counted-vmcnt prefetch across raw s_barrier. DISTRIBUTED q-state: wave
// (kq,qh) owns rows [8kq,8kq+8) of its qh group -> only 8 f32/thread; total
// (arch+acc) VGPR fits the 128/thread budget of __launch_bounds__(512,4)
// -> 4 waves/SIMD, 2 blocks/CU. Symmetric dump + distributed merge.
__global__ __launch_bounds__(512, 4) void attn5(
    const u16* __restrict__ Kbf,   // [NH][NCTX][HD], pre-scaled by beta*log2e
    const u16* __restrict__ Ktb,   // [NH][HD][NCTX]
    const float* __restrict__ Qf,  // [NTGT][DMODEL]
    u16* __restrict__ Qob) {       // [NTGT][DMODEL] bf16
  __shared__ __align__(16) u16 sTu[32768];   // 64KB: 2x32KB tile buffers
  __shared__ float lb[8][32];                // 1KB: per-wave row-sum partials

  const int bid = blockIdx.x;
  const int h  = ((bid & 7) << 1) | ((bid >> 3) & 1);
  const int qt = bid >> 4;
  const int w = threadIdx.x >> 6, l = threadIdx.x & 63;
  const int ln = l & 31, hi = l >> 5;
  const int qh = w & 1, kq = w >> 1;
  const int q0w = qt * 64 + qh * 32;

  const u16* Kh  = Kbf + (size_t)h * NCTX * HD;
  const u16* Kth = Ktb + (size_t)h * HD * NCTX;

  auto STAGE = [&](int b, int t) {
#pragma unroll
    for (int i = 0; i < 2; ++i) {
      const u16* src = Kh + (size_t)(t * 128 + w * 16 + i * 8 + (l >> 3)) * HD
                          + (((l & 7) ^ (l >> 3) ^ ((w * 2 + i) & 7)) << 3);
      __builtin_amdgcn_global_load_lds((g_u32*)src,
          (lds_u32*)(sTu + b * 16384 + (w * 16 + i * 8) * 64), 16, 0, 0);
    }
#pragma unroll
    for (int i = 0; i < 2; ++i) {
      const u16* src = Kth + (size_t)(w * 8 + i * 4 + (l >> 4)) * NCTX + t * 128
                           + (((l & 15) ^ ((w * 8 + i * 4 + (l >> 4)) & 15)) << 3);
      __builtin_amdgcn_global_load_lds((g_u32*)src,
          (lds_u32*)(sTu + b * 16384 + 8192 + (w * 8 + i * 4) * 128), 16, 0, 0);
    }
  };

  // ---- Q B-frags: lane q=ln, z = zc*16 + 8*hi + e ----
  short8 qfrag[4];
  {
    const float* qp = Qf + (size_t)(q0w + ln) * DMODEL + h * HD + hi * 8;
#pragma unroll
    for (int zc = 0; zc < 4; ++zc) qfrag[zc] = ld8f(qp + zc * 16);
  }
  // ---- distributed q-state: rows qq = i + 8*kq + 4*hi, cols ln / 32+ln ----
  float qst0[4], qst1[4];
#pragma unroll
  for (int i = 0; i < 4; ++i) {
    const int qq = i + 8 * kq + 4 * hi;
    const float* qp = Qf + (size_t)(q0w + qq) * DMODEL + h * HD;
    qst0[i] = qp[ln];
    qst1[i] = qp[32 + ln];
  }

  STAGE(0, 0);

  for (int step = 0; step < 5; ++step) {
    f32x16 acc0 = {}, acc1 = {};
    float lrow = 0.f;

#pragma unroll 2
    for (int t = 0; t < 32; ++t) {
      const int buf = t & 1;
      asm volatile("s_waitcnt vmcnt(0)" ::: "memory");  // own tile-t loads done
      __builtin_amdgcn_s_barrier();                     // everyone's tile-t done
      if (t < 31) STAGE(buf ^ 1, t + 1);                // prefetch stays in flight
      const u16* tb = sTu + buf * 16384;

      // ---- St = K_strip * Q^T (k rows kq*32+ln, q cols = lanes) ----
      f32x16 st = {};
#pragma unroll
      for (int zc = 0; zc < 4; ++zc) {
        const int b7 = (zc * 2 + hi) ^ (ln & 7) ^ ((kq * 4 + (ln >> 3)) & 7);
        short8 kf = *(const short8*)(tb + (kq * 32 + ln) * 64 + (b7 << 3));
        st = __builtin_amdgcn_mfma_f32_32x32x16_bf16(kf, qfrag[zc], st, 0, 0, 0);
      }
      // ---- P = exp2(St); pack via cvt_pk + permlane32_swap; PV ----
      const u16* kt = tb + 8192;
#pragma unroll
      for (int kc = 0; kc < 2; ++kc) {
        float p0 = exp2f(st[8 * kc + 0]), p1 = exp2f(st[8 * kc + 1]);
        float p2 = exp2f(st[8 * kc + 2]), p3 = exp2f(st[8 * kc + 3]);
        float p4 = exp2f(st[8 * kc + 4]), p5 = exp2f(st[8 * kc + 5]);
        float p6 = exp2f(st[8 * kc + 6]), p7 = exp2f(st[8 * kc + 7]);
        lrow += ((p0 + p1) + (p2 + p3)) + ((p4 + p5) + (p6 + p7));
        uint32_t a0 = pk2(p0, p1), a1 = pk2(p2, p3);
        uint32_t b0 = pk2(p4, p5), b1 = pk2(p6, p7);
        asm("v_permlane32_swap_b32 %0, %1" : "+v"(a0), "+v"(b0));
        asm("v_permlane32_swap_b32 %0, %1" : "+v"(a1), "+v"(b1));
        union { short8 s; uint32_t u[4]; } pa;
        pa.u[0] = a0; pa.u[1] = a1; pa.u[2] = b0; pa.u[3] = b1;
        const int b16 = (kq * 4 + kc * 2 + hi) ^ (ln & 15);
        short8 v0 = *(const short8*)(kt + ln * 128 + (b16 << 3));
        short8 v1 = *(const short8*)(kt + (32 + ln) * 128 + (b16 << 3));
        acc0 = __builtin_amdgcn_mfma_f32_32x32x16_bf16(pa.s, v0, acc0, 0, 0, 0);
        acc1 = __builtin_amdgcn_mfma_f32_32x32x16_bf16(pa.s, v1, acc1, 0, 0, 0);
      }
    }

    __syncthreads();                       // all compute done; sTu free
    lrow += __shfl_xor(lrow, 32);

    // ---- symmetric dump: all 8 waves write their partials ----
    float* md = (float*)sTu;               // 8 regions x 8KB = 64KB
    float* my = md + (kq * 2 + qh) * 2048;
#pragma unroll
    for (int rr = 0; rr < 16; ++rr) {
      my[rr * 64 + l] = acc0[rr];
      my[(rr + 16) * 64 + l] = acc1[rr];
    }
    if (hi == 0) lb[kq * 2 + qh][ln] = lrow;
    __syncthreads();

    // ---- distributed merge: wave (kq,qh) handles rr in [4kq, 4kq+4) ----
#pragma unroll
    for (int i = 0; i < 4; ++i) {
      const int rr = 4 * kq + i;
      const int qq = i + 8 * kq + 4 * hi;
      const float o0 = md[qh * 2048 + rr * 64 + l] + md[(2 + qh) * 2048 + rr * 64 + l]
                     + md[(4 + qh) * 2048 + rr * 64 + l] + md[(6 + qh) * 2048 + rr * 64 + l];
      const float o1 = md[qh * 2048 + (rr + 16) * 64 + l] + md[(2 + qh) * 2048 + (rr + 16) * 64 + l]
                     + md[(4 + qh) * 2048 + (rr + 16) * 64 + l] + md[(6 + qh) * 2048 + (rr + 16) * 64 + l];
      const float lt = lb[qh][qq] + lb[2 + qh][qq] + lb[4 + qh][qq] + lb[6 + qh][qq];
      const float sc = 0.1f / lt;
      qst0[i] += o0 * sc;
      qst1[i] += o1 * sc;
    }

    if (step < 4) {
      __syncthreads();                     // all dump reads done; region 6 free
      u16* qsm = sTu + 24576 + qh * 2048;  // bytes [48K,56K), overlays region 6
#pragma unroll
      for (int i = 0; i < 4; ++i) {
        const int qq = i + 8 * kq + 4 * hi;
        qsm[qq * 64 + ((((ln >> 3)) ^ (qq & 7)) << 3) + (ln & 7)] = f2b(qst0[i]);
        qsm[qq * 64 + ((((ln >> 3) + 4) ^ (qq & 7)) << 3) + (ln & 7)] = f2b(qst1[i]);
      }
      __syncthreads();                     // qs16 visible to all waves
      const u16* qsr = sTu + 24576 + qh * 2048;
#pragma unroll
      for (int zc = 0; zc < 4; ++zc)
        qfrag[zc] = *(const short8*)(qsr + ln * 64 + (((zc * 2 + hi) ^ (ln & 7)) << 3));
      STAGE(0, 0);                         // writes bytes [0, 32K), no overlap
    } else {
#pragma unroll
      for (int i = 0; i < 4; ++i) {
        const int qq = i + 8 * kq + 4 * hi;
        const size_t base = (size_t)(q0w + qq) * DMODEL + h * HD;
        Qob[base + ln] = f2b(qst0[i]);
        Qob[base + 32 + ln] = f2b(qst1[i]);
      }
    }
  }
}

extern "C" void kernel_launch(void* const* d_in, const int* in_sizes, int n_in,
                              void* d_out, int out_size, void* d_ws, size_t ws_size,
                              hipStream_t stream) {
  const float* ctx = (const float*)d_in[0];
  const float* tgt = (const float*)d_in[1];
  const float* Wq  = (const float*)d_in[2];
  const float* Wk  = (const float*)d_in[3];
  const float* Wo  = (const float*)d_in[4];

  uint8_t* wp = (uint8_t*)d_ws;
  u16* Kbf  = (u16*)wp; wp += (size_t)NH * NCTX * HD * 2;
  u16* Ktb  = (u16*)wp; wp += (size_t)NH * HD * NCTX * 2;
  float* Qf = (float*)wp; wp += (size_t)NTGT * DMODEL * 4;
  u16* Qob  = (u16*)wp; wp += (size_t)NTGT * DMODEL * 2;

  // K projection: f32 ctx x f32 Wk -> Ck (bf16, pre-scaled) + Ckt (bf16)
  hipLaunchKernelGGL((gemm_bt<1, 1, 1>), dim3((NCTX / 64) * (DMODEL / 64)), dim3(256), 0, stream,
                     (const void*)ctx, (const void*)Wk, (float*)nullptr, Kbf, Ktb,
                     NCTX, DMODEL, DMODEL);
  // Q projection: f32 tgt x f32 Wq -> Qf (f32)
  hipLaunchKernelGGL((gemm_bt<0, 1, 1>), dim3((NTGT / 64) * (DMODEL / 64)), dim3(256), 0, stream,
                     (const void*)tgt, (const void*)Wq, Qf, (u16*)nullptr, (u16*)nullptr,
                     NTGT, DMODEL, DMODEL);
  // 5-step energy attention
  hipLaunchKernelGGL(attn5, dim3(512), dim3(512), 0, stream, Kbf, Ktb, Qf, Qob);
  // Output projection: bf16 Qob x f32 Wo -> d_out (f32)
  hipLaunchKernelGGL((gemm_bt<0, 0, 1>), dim3((NTGT / 64) * (DMODEL / 64)), dim3(256), 0, stream,
                     (const void*)Qob, (const void*)Wo, (float*)d_out, (u16*)nullptr, (u16*)nullptr,
                     NTGT, DMODEL, DMODEL);
}

// Round 17
// 444.302 us; speedup vs baseline: 1.2607x; 1.2607x over previous
//
#include <hip/hip_runtime.h>
#include <stdint.h>

typedef unsigned short u16;
typedef __attribute__((ext_vector_type(8))) short short8;
typedef __attribute__((ext_vector_type(4))) float f32x4;
typedef __attribute__((ext_vector_type(16))) float f32x16;

#define NCTX 4096
#define NTGT 2048
#define DMODEL 1024
#define NH 16
#define HD 64

typedef const __attribute__((address_space(1))) uint32_t g_u32;
typedef __attribute__((address_space(3))) uint32_t lds_u32;

__device__ inline u16 f2b(float f) {
  unsigned r;
  asm("v_cvt_pk_bf16_f32 %0, %1, %1" : "=v"(r) : "v"(f));
  return (u16)r;
}
__device__ inline uint32_t pk2(float lo, float hi_) {
  uint32_t r;
  asm("v_cvt_pk_bf16_f32 %0, %1, %2" : "=v"(r) : "v"(lo), "v"(hi_));
  return r;
}

// ---------------- f32 -> bf16 conversion ----------------
__global__ void cvt_bf16(const float* __restrict__ in, u16* __restrict__ out, int n4) {
  int i = blockIdx.x * blockDim.x + threadIdx.x;
  if (i >= n4) return;
  const float4 v = ((const float4*)in)[i];
  ((uint2*)out)[i] = make_uint2(pk2(v.x, v.y), pk2(v.z, v.w));
}

// ---------------- generic C = A * B^T  (bf16 in, f32 accum) ----------------
// MODE 1: K-writer; Ck is pre-scaled by beta*log2e (used only for scores).
template<int MODE>
__global__ __launch_bounds__(256) void gemm_bt(
    const u16* __restrict__ A, const u16* __restrict__ B,
    float* __restrict__ Cf, u16* __restrict__ Ck, u16* __restrict__ Ckt,
    int M, int N, int Kd) {
  const int bm = blockIdx.x % (M >> 6);
  const int bn = blockIdx.x / (M >> 6);
  const int w = threadIdx.x >> 6, l = threadIdx.x & 63;
  const int lg = l >> 4, lm = l & 15;
  const int m0 = (bm << 6) + (w << 4);
  const int n0 = bn << 6;

  const u16* Ar = A + (size_t)(m0 + lm) * Kd;
  f32x4 acc[4] = {};

  for (int kd = 0; kd < Kd; kd += 64) {
    short8 a0 = *(const short8*)(Ar + kd + lg * 8);
    short8 a1 = *(const short8*)(Ar + kd + 32 + lg * 8);
#pragma unroll
    for (int nf = 0; nf < 4; ++nf) {
      const u16* Br = B + (size_t)(n0 + nf * 16 + lm) * Kd + kd + lg * 8;
      short8 b0 = *(const short8*)(Br);
      short8 b1 = *(const short8*)(Br + 32);
      acc[nf] = __builtin_amdgcn_mfma_f32_16x16x32_bf16(a0, b0, acc[nf], 0, 0, 0);
      acc[nf] = __builtin_amdgcn_mfma_f32_16x16x32_bf16(a1, b1, acc[nf], 0, 0, 0);
    }
  }

  if (MODE == 0) {
#pragma unroll
    for (int nf = 0; nf < 4; ++nf)
#pragma unroll
      for (int r = 0; r < 4; ++r)
        Cf[(size_t)(m0 + lg * 4 + r) * N + (n0 + nf * 16 + lm)] = acc[nf][r];
  } else {
    const float BL2E = 0.125f * 1.44269504088896340736f;
#pragma unroll
    for (int nf = 0; nf < 4; ++nf) {
      int n = n0 + nf * 16 + lm;
      int h = n >> 6, z = n & 63;
#pragma unroll
      for (int r = 0; r < 4; ++r) {
        int k = m0 + lg * 4 + r;
        Ck[((size_t)h * NCTX + k) * HD + z] = f2b(acc[nf][r] * BL2E);
        Ckt[((size_t)h * HD + z) * NCTX + k] = f2b(acc[nf][r]);
      }
    }
  }
}

// ---------------- 5-step energy attention, 8-wave / 128-k tiles ----------------
// 512 blocks = 16 heads x 32 q-tiles of 64 rows; 512 threads = 8 waves
// (kq 0-3 x qh 0-1). Staged tile: K 128x64 + Kt 64x128, double-buffered (64KB).
// Counted-vmcnt prefetch across raw s_barrier. DISTRIBUTED q-state (8 f32/thr)
// keeps total VGPR in the 128/thread budget of (512,4) -> 4 waves/SIMD,
// 2 blocks/CU. Symmetric dump + distributed merge. s_setprio(1) around MFMA
// clusters (T5: pays when waves have role diversity, harmless otherwise).
__global__ __launch_bounds__(512, 4) void attn5(
    const u16* __restrict__ Kbf,   // [NH][NCTX][HD], pre-scaled by beta*log2e
    const u16* __restrict__ Ktb,   // [NH][HD][NCTX]
    const float* __restrict__ Qf,  // [NTGT][DMODEL]
    u16* __restrict__ Qob) {       // [NTGT][DMODEL] bf16
  __shared__ __align__(16) u16 sTu[32768];   // 64KB: 2x32KB tile buffers
  __shared__ float lb[8][32];                // 1KB: per-wave row-sum partials

  const int bid = blockIdx.x;
  const int h  = ((bid & 7) << 1) | ((bid >> 3) & 1);
  const int qt = bid >> 4;
  const int w = threadIdx.x >> 6, l = threadIdx.x & 63;
  const int ln = l & 31, hi = l >> 5;
  const int qh = w & 1, kq = w >> 1;
  const int q0w = qt * 64 + qh * 32;

  const u16* Kh  = Kbf + (size_t)h * NCTX * HD;
  const u16* Kth = Ktb + (size_t)h * HD * NCTX;

  auto STAGE = [&](int b, int t) {
#pragma unroll
    for (int i = 0; i < 2; ++i) {
      const u16* src = Kh + (size_t)(t * 128 + w * 16 + i * 8 + (l >> 3)) * HD
                          + (((l & 7) ^ (l >> 3) ^ ((w * 2 + i) & 7)) << 3);
      __builtin_amdgcn_global_load_lds((g_u32*)src,
          (lds_u32*)(sTu + b * 16384 + (w * 16 + i * 8) * 64), 16, 0, 0);
    }
#pragma unroll
    for (int i = 0; i < 2; ++i) {
      const u16* src = Kth + (size_t)(w * 8 + i * 4 + (l >> 4)) * NCTX + t * 128
                           + (((l & 15) ^ ((w * 8 + i * 4 + (l >> 4)) & 15)) << 3);
      __builtin_amdgcn_global_load_lds((g_u32*)src,
          (lds_u32*)(sTu + b * 16384 + 8192 + (w * 8 + i * 4) * 128), 16, 0, 0);
    }
  };

  // ---- Q B-frags: lane q=ln, z = zc*16 + 8*hi + e ----
  short8 qfrag[4];
  {
    const float* qp = Qf + (size_t)(q0w + ln) * DMODEL + h * HD + hi * 8;
#pragma unroll
    for (int zc = 0; zc < 4; ++zc) {
      float4 f0 = *(const float4*)(qp + zc * 16);
      float4 f1 = *(const float4*)(qp + zc * 16 + 4);
      union { short8 s; uint32_t u[4]; } t;
      t.u[0] = pk2(f0.x, f0.y); t.u[1] = pk2(f0.z, f0.w);
      t.u[2] = pk2(f1.x, f1.y); t.u[3] = pk2(f1.z, f1.w);
      qfrag[zc] = t.s;
    }
  }
  // ---- distributed q-state: rows qq = i + 8*kq + 4*hi, cols ln / 32+ln ----
  float qst0[4], qst1[4];
#pragma unroll
  for (int i = 0; i < 4; ++i) {
    const int qq = i + 8 * kq + 4 * hi;
    const float* qp = Qf + (size_t)(q0w + qq) * DMODEL + h * HD;
    qst0[i] = qp[ln];
    qst1[i] = qp[32 + ln];
  }

  STAGE(0, 0);

  for (int step = 0; step < 5; ++step) {
    f32x16 acc0 = {}, acc1 = {};
    float lrow = 0.f;

#pragma unroll 2
    for (int t = 0; t < 32; ++t) {
      const int buf = t & 1;
      asm volatile("s_waitcnt vmcnt(0)" ::: "memory");  // own tile-t loads done
      __builtin_amdgcn_s_barrier();                     // everyone's tile-t done
      if (t < 31) STAGE(buf ^ 1, t + 1);                // prefetch stays in flight
      const u16* tb = sTu + buf * 16384;

      // ---- St = K_strip * Q^T (k rows kq*32+ln, q cols = lanes) ----
      f32x16 st = {};
      __builtin_amdgcn_s_setprio(1);
#pragma unroll
      for (int zc = 0; zc < 4; ++zc) {
        const int b7 = (zc * 2 + hi) ^ (ln & 7) ^ ((kq * 4 + (ln >> 3)) & 7);
        short8 kf = *(const short8*)(tb + (kq * 32 + ln) * 64 + (b7 << 3));
        st = __builtin_amdgcn_mfma_f32_32x32x16_bf16(kf, qfrag[zc], st, 0, 0, 0);
      }
      __builtin_amdgcn_s_setprio(0);
      // ---- P = exp2(St); pack via cvt_pk + permlane32_swap; PV ----
      const u16* kt = tb + 8192;
#pragma unroll
      for (int kc = 0; kc < 2; ++kc) {
        float p0 = exp2f(st[8 * kc + 0]), p1 = exp2f(st[8 * kc + 1]);
        float p2 = exp2f(st[8 * kc + 2]), p3 = exp2f(st[8 * kc + 3]);
        float p4 = exp2f(st[8 * kc + 4]), p5 = exp2f(st[8 * kc + 5]);
        float p6 = exp2f(st[8 * kc + 6]), p7 = exp2f(st[8 * kc + 7]);
        lrow += ((p0 + p1) + (p2 + p3)) + ((p4 + p5) + (p6 + p7));
        uint32_t a0 = pk2(p0, p1), a1 = pk2(p2, p3);
        uint32_t b0 = pk2(p4, p5), b1 = pk2(p6, p7);
        asm("v_permlane32_swap_b32 %0, %1" : "+v"(a0), "+v"(b0));
        asm("v_permlane32_swap_b32 %0, %1" : "+v"(a1), "+v"(b1));
        union { short8 s; uint32_t u[4]; } pa;
        pa.u[0] = a0; pa.u[1] = a1; pa.u[2] = b0; pa.u[3] = b1;
        const int b16 = (kq * 4 + kc * 2 + hi) ^ (ln & 15);
        short8 v0 = *(const short8*)(kt + ln * 128 + (b16 << 3));
        short8 v1 = *(const short8*)(kt + (32 + ln) * 128 + (b16 << 3));
        __builtin_amdgcn_s_setprio(1);
        acc0 = __builtin_amdgcn_mfma_f32_32x32x16_bf16(pa.s, v0, acc0, 0, 0, 0);
        acc1 = __builtin_amdgcn_mfma_f32_32x32x16_bf16(pa.s, v1, acc1, 0, 0, 0);
        __builtin_amdgcn_s_setprio(0);
      }
    }

    __syncthreads();                       // all compute done; sTu free
    lrow += __shfl_xor(lrow, 32);

    // ---- symmetric dump: all 8 waves write their partials ----
    float* md = (float*)sTu;               // 8 regions x 8KB = 64KB
    float* my = md + (kq * 2 + qh) * 2048;
#pragma unroll
    for (int rr = 0; rr < 16; ++rr) {
      my[rr * 64 + l] = acc0[rr];
      my[(rr + 16) * 64 + l] = acc1[rr];
    }
    if (hi == 0) lb[kq * 2 + qh][ln] = lrow;
    __syncthreads();

    // ---- distributed merge: wave (kq,qh) handles rr in [4kq, 4kq+4) ----
#pragma unroll
    for (int i = 0; i < 4; ++i) {
      const int rr = 4 * kq + i;
      const int qq = i + 8 * kq + 4 * hi;
      const float o0 = md[qh * 2048 + rr * 64 + l] + md[(2 + qh) * 2048 + rr * 64 + l]
                     + md[(4 + qh) * 2048 + rr * 64 + l] + md[(6 + qh) * 2048 + rr * 64 + l];
      const float o1 = md[qh * 2048 + (rr + 16) * 64 + l] + md[(2 + qh) * 2048 + (rr + 16) * 64 + l]
                     + md[(4 + qh) * 2048 + (rr + 16) * 64 + l] + md[(6 + qh) * 2048 + (rr + 16) * 64 + l];
      const float lt = lb[qh][qq] + lb[2 + qh][qq] + lb[4 + qh][qq] + lb[6 + qh][qq];
      const float sc = 0.1f / lt;
      qst0[i] += o0 * sc;
      qst1[i] += o1 * sc;
    }

    if (step < 4) {
      __syncthreads();                     // all dump reads done; region 6 free
      u16* qsm = sTu + 24576 + qh * 2048;  // bytes [48K,56K), overlays region 6
#pragma unroll
      for (int i = 0; i < 4; ++i) {
        const int qq = i + 8 * kq + 4 * hi;
        qsm[qq * 64 + ((((ln >> 3)) ^ (qq & 7)) << 3) + (ln & 7)] = f2b(qst0[i]);
        qsm[qq * 64 + ((((ln >> 3) + 4) ^ (qq & 7)) << 3) + (ln & 7)] = f2b(qst1[i]);
      }
      __syncthreads();                     // qs16 visible to all waves
      const u16* qsr = sTu + 24576 + qh * 2048;
#pragma unroll
      for (int zc = 0; zc < 4; ++zc)
        qfrag[zc] = *(const short8*)(qsr + ln * 64 + (((zc * 2 + hi) ^ (ln & 7)) << 3));
      STAGE(0, 0);                         // writes bytes [0, 32K), no overlap
    } else {
#pragma unroll
      for (int i = 0; i < 4; ++i) {
        const int qq = i + 8 * kq + 4 * hi;
        const size_t base = (size_t)(q0w + qq) * DMODEL + h * HD;
        Qob[base + ln] = f2b(qst0[i]);
        Qob[base + 32 + ln] = f2b(qst1[i]);
      }
    }
  }
}

extern "C" void kernel_launch(void* const* d_in, const int* in_sizes, int n_in,
                              void* d_out, int out_size, void* d_ws, size_t ws_size,
                              hipStream_t stream) {
  const float* ctx = (const float*)d_in[0];
  const float* tgt = (const float*)d_in[1];
  const float* Wq  = (const float*)d_in[2];
  const float* Wk  = (const float*)d_in[3];
  const float* Wo  = (const float*)d_in[4];

  uint8_t* wp = (uint8_t*)d_ws;
  u16* ctxb = (u16*)wp; wp += (size_t)NCTX * DMODEL * 2;
  u16* tgtb = (u16*)wp; wp += (size_t)NTGT * DMODEL * 2;
  u16* wqb  = (u16*)wp; wp += (size_t)DMODEL * DMODEL * 2;
  u16* wkb  = (u16*)wp; wp += (size_t)DMODEL * DMODEL * 2;
  u16* wob  = (u16*)wp; wp += (size_t)DMODEL * DMODEL * 2;
  u16* Kbf  = (u16*)wp; wp += (size_t)NH * NCTX * HD * 2;
  u16* Ktb  = (u16*)wp; wp += (size_t)NH * HD * NCTX * 2;
  float* Qf = (float*)wp; wp += (size_t)NTGT * DMODEL * 4;
  u16* Qob  = (u16*)wp; wp += (size_t)NTGT * DMODEL * 2;

  auto cvt = [&](const float* in, u16* out, size_t n) {
    int n4 = (int)(n / 4);
    hipLaunchKernelGGL(cvt_bf16, dim3((n4 + 255) / 256), dim3(256), 0, stream, in, out, n4);
  };
  cvt(ctx, ctxb, (size_t)NCTX * DMODEL);
  cvt(tgt, tgtb, (size_t)NTGT * DMODEL);
  cvt(Wq, wqb, (size_t)DMODEL * DMODEL);
  cvt(Wk, wkb, (size_t)DMODEL * DMODEL);
  cvt(Wo, wob, (size_t)DMODEL * DMODEL);

  hipLaunchKernelGGL(gemm_bt<1>, dim3((NCTX / 64) * (DMODEL / 64)), dim3(256), 0, stream,
                     ctxb, wkb, (float*)nullptr, Kbf, Ktb, NCTX, DMODEL, DMODEL);
  hipLaunchKernelGGL(gemm_bt<0>, dim3((NTGT / 64) * (DMODEL / 64)), dim3(256), 0, stream,
                     tgtb, wqb, Qf, (u16*)nullptr, (u16*)nullptr, NTGT, DMODEL, DMODEL);
  hipLaunchKernelGGL(attn5, dim3(512), dim3(512), 0, stream, Kbf, Ktb, Qf, Qob);
  hipLaunchKernelGGL(gemm_bt<0>, dim3((NTGT / 64) * (DMODEL / 64)), dim3(256), 0, stream,
                     Qob, wob, (float*)d_out, (u16*)nullptr, (u16*)nullptr, NTGT, DMODEL, DMODEL);
}

// Round 18
// 433.496 us; speedup vs baseline: 1.2922x; 1.0249x over previous
//
#include <hip/hip_runtime.h>
#include <stdint.h>

typedef unsigned short u16;
typedef __attribute__((ext_vector_type(8))) short short8;
typedef __attribute__((ext_vector_type(4))) float f32x4;
typedef __attribute__((ext_vector_type(16))) float f32x16;

#define NCTX 4096
#define NTGT 2048
#define DMODEL 1024
#define NH 16
#define HD 64

typedef const __attribute__((address_space(1))) uint32_t g_u32;
typedef __attribute__((address_space(3))) uint32_t lds_u32;

__device__ inline u16 f2b(float f) {
  unsigned r;
  asm("v_cvt_pk_bf16_f32 %0, %1, %1" : "=v"(r) : "v"(f));
  return (u16)r;
}
__device__ inline uint32_t pk2(float lo, float hi_) {
  uint32_t r;
  asm("v_cvt_pk_bf16_f32 %0, %1, %2" : "=v"(r) : "v"(lo), "v"(hi_));
  return r;
}

// ---------------- fused f32 -> bf16 conversion (all 5 tensors, 1 launch) ----------------
__global__ void cvt_fused(const float* s0, u16* d0, int n0,
                          const float* s1, u16* d1, int n1,
                          const float* s2, u16* d2, int n2,
                          const float* s3, u16* d3, int n3,
                          const float* s4, u16* d4, int n4) {
  const int total = n0 + n1 + n2 + n3 + n4;
  for (int i = blockIdx.x * blockDim.x + threadIdx.x; i < total; i += gridDim.x * blockDim.x) {
    const float* s; u16* d; int j = i;
    if (j < n0) { s = s0; d = d0; }
    else if ((j -= n0) < n1) { s = s1; d = d1; }
    else if ((j -= n1) < n2) { s = s2; d = d2; }
    else if ((j -= n2) < n3) { s = s3; d = d3; }
    else { j -= n3; s = s4; d = d4; }
    const float4 v = ((const float4*)s)[j];
    ((uint2*)d)[j] = make_uint2(pk2(v.x, v.y), pk2(v.z, v.w));
  }
}

// ---------------- generic C = A * B^T body (bf16 in, f32 accum) ----------------
// MODE 1: K-writer; Ck is pre-scaled by beta*log2e (used only for scores).
template<int MODE>
__device__ __forceinline__ void gemm_body(
    const u16* __restrict__ A, const u16* __restrict__ B,
    float* __restrict__ Cf, u16* __restrict__ Ck, u16* __restrict__ Ckt,
    int M, int N, int Kd, int bid, int tid) {
  const int bm = bid % (M >> 6);
  const int bn = bid / (M >> 6);
  const int w = tid >> 6, l = tid & 63;
  const int lg = l >> 4, lm = l & 15;
  const int m0 = (bm << 6) + (w << 4);
  const int n0 = bn << 6;

  const u16* Ar = A + (size_t)(m0 + lm) * Kd;
  f32x4 acc[4] = {};

  for (int kd = 0; kd < Kd; kd += 64) {
    short8 a0 = *(const short8*)(Ar + kd + lg * 8);
    short8 a1 = *(const short8*)(Ar + kd + 32 + lg * 8);
#pragma unroll
    for (int nf = 0; nf < 4; ++nf) {
      const u16* Br = B + (size_t)(n0 + nf * 16 + lm) * Kd + kd + lg * 8;
      short8 b0 = *(const short8*)(Br);
      short8 b1 = *(const short8*)(Br + 32);
      acc[nf] = __builtin_amdgcn_mfma_f32_16x16x32_bf16(a0, b0, acc[nf], 0, 0, 0);
      acc[nf] = __builtin_amdgcn_mfma_f32_16x16x32_bf16(a1, b1, acc[nf], 0, 0, 0);
    }
  }

  if (MODE == 0) {
#pragma unroll
    for (int nf = 0; nf < 4; ++nf)
#pragma unroll
      for (int r = 0; r < 4; ++r)
        Cf[(size_t)(m0 + lg * 4 + r) * N + (n0 + nf * 16 + lm)] = acc[nf][r];
  } else {
    const float BL2E = 0.125f * 1.44269504088896340736f;
#pragma unroll
    for (int nf = 0; nf < 4; ++nf) {
      int n = n0 + nf * 16 + lm;
      int h = n >> 6, z = n & 63;
#pragma unroll
      for (int r = 0; r < 4; ++r) {
        int k = m0 + lg * 4 + r;
        Ck[((size_t)h * NCTX + k) * HD + z] = f2b(acc[nf][r] * BL2E);
        Ckt[((size_t)h * HD + z) * NCTX + k] = f2b(acc[nf][r]);
      }
    }
  }
}

// K-proj (blocks [0,1024)) + Q-proj (blocks [1024,1536)) in one dispatch.
__global__ __launch_bounds__(256) void proj_kq(
    const u16* __restrict__ ctxb, const u16* __restrict__ wkb,
    const u16* __restrict__ tgtb, const u16* __restrict__ wqb,
    u16* __restrict__ Kbf, u16* __restrict__ Ktb, float* __restrict__ Qf) {
  if (blockIdx.x < (NCTX / 64) * (DMODEL / 64))
    gemm_body<1>(ctxb, wkb, nullptr, Kbf, Ktb, NCTX, DMODEL, DMODEL,
                 blockIdx.x, threadIdx.x);
  else
    gemm_body<0>(tgtb, wqb, Qf, nullptr, nullptr, NTGT, DMODEL, DMODEL,
                 blockIdx.x - (NCTX / 64) * (DMODEL / 64), threadIdx.x);
}

__global__ __launch_bounds__(256) void gemm_c(
    const u16* __restrict__ A, const u16* __restrict__ B, float* __restrict__ Cf,
    int M, int N, int Kd) {
  gemm_body<0>(A, B, Cf, nullptr, nullptr, M, N, Kd, blockIdx.x, threadIdx.x);
}

// ---------------- 5-step energy attention, 8-wave / 128-k tiles ----------------
// 512 blocks = 16 heads x 32 q-tiles of 64 rows; 512 threads = 8 waves
// (kq 0-3 x qh 0-1). Staged tile: K 128x64 + Kt 64x128, double-buffered (64KB).
// Counted-vmcnt prefetch across raw s_barrier. DISTRIBUTED q-state (8 f32/thr)
// keeps total VGPR in the 128/thread budget of (512,4) -> 4 waves/SIMD,
// 2 blocks/CU. Symmetric dump + distributed merge. setprio around MFMAs (T5).
__global__ __launch_bounds__(512, 4) void attn5(
    const u16* __restrict__ Kbf,   // [NH][NCTX][HD], pre-scaled by beta*log2e
    const u16* __restrict__ Ktb,   // [NH][HD][NCTX]
    const float* __restrict__ Qf,  // [NTGT][DMODEL]
    u16* __restrict__ Qob) {       // [NTGT][DMODEL] bf16
  __shared__ __align__(16) u16 sTu[32768];   // 64KB: 2x32KB tile buffers
  __shared__ float lb[8][32];                // 1KB: per-wave row-sum partials

  const int bid = blockIdx.x;
  const int h  = ((bid & 7) << 1) | ((bid >> 3) & 1);
  const int qt = bid >> 4;
  const int w = threadIdx.x >> 6, l = threadIdx.x & 63;
  const int ln = l & 31, hi = l >> 5;
  const int qh = w & 1, kq = w >> 1;
  const int q0w = qt * 64 + qh * 32;

  const u16* Kh  = Kbf + (size_t)h * NCTX * HD;
  const u16* Kth = Ktb + (size_t)h * HD * NCTX;

  auto STAGE = [&](int b, int t) {
#pragma unroll
    for (int i = 0; i < 2; ++i) {
      const u16* src = Kh + (size_t)(t * 128 + w * 16 + i * 8 + (l >> 3)) * HD
                          + (((l & 7) ^ (l >> 3) ^ ((w * 2 + i) & 7)) << 3);
      __builtin_amdgcn_global_load_lds((g_u32*)src,
          (lds_u32*)(sTu + b * 16384 + (w * 16 + i * 8) * 64), 16, 0, 0);
    }
#pragma unroll
    for (int i = 0; i < 2; ++i) {
      const u16* src = Kth + (size_t)(w * 8 + i * 4 + (l >> 4)) * NCTX + t * 128
                           + (((l & 15) ^ ((w * 8 + i * 4 + (l >> 4)) & 15)) << 3);
      __builtin_amdgcn_global_load_lds((g_u32*)src,
          (lds_u32*)(sTu + b * 16384 + 8192 + (w * 8 + i * 4) * 128), 16, 0, 0);
    }
  };

  // ---- Q B-frags: lane q=ln, z = zc*16 + 8*hi + e ----
  short8 qfrag[4];
  {
    const float* qp = Qf + (size_t)(q0w + ln) * DMODEL + h * HD + hi * 8;
#pragma unroll
    for (int zc = 0; zc < 4; ++zc) {
      float4 f0 = *(const float4*)(qp + zc * 16);
      float4 f1 = *(const float4*)(qp + zc * 16 + 4);
      union { short8 s; uint32_t u[4]; } t;
      t.u[0] = pk2(f0.x, f0.y); t.u[1] = pk2(f0.z, f0.w);
      t.u[2] = pk2(f1.x, f1.y); t.u[3] = pk2(f1.z, f1.w);
      qfrag[zc] = t.s;
    }
  }
  // ---- distributed q-state: rows qq = i + 8*kq + 4*hi, cols ln / 32+ln ----
  float qst0[4], qst1[4];
#pragma unroll
  for (int i = 0; i < 4; ++i) {
    const int qq = i + 8 * kq + 4 * hi;
    const float* qp = Qf + (size_t)(q0w + qq) * DMODEL + h * HD;
    qst0[i] = qp[ln];
    qst1[i] = qp[32 + ln];
  }

  STAGE(0, 0);

  for (int step = 0; step < 5; ++step) {
    f32x16 acc0 = {}, acc1 = {};
    float lrow = 0.f;

#pragma unroll 2
    for (int t = 0; t < 32; ++t) {
      const int buf = t & 1;
      asm volatile("s_waitcnt vmcnt(0)" ::: "memory");  // own tile-t loads done
      __builtin_amdgcn_s_barrier();                     // everyone's tile-t done
      if (t < 31) STAGE(buf ^ 1, t + 1);                // prefetch stays in flight
      const u16* tb = sTu + buf * 16384;

      // ---- St = K_strip * Q^T (k rows kq*32+ln, q cols = lanes) ----
      f32x16 st = {};
      __builtin_amdgcn_s_setprio(1);
#pragma unroll
      for (int zc = 0; zc < 4; ++zc) {
        const int b7 = (zc * 2 + hi) ^ (ln & 7) ^ ((kq * 4 + (ln >> 3)) & 7);
        short8 kf = *(const short8*)(tb + (kq * 32 + ln) * 64 + (b7 << 3));
        st = __builtin_amdgcn_mfma_f32_32x32x16_bf16(kf, qfrag[zc], st, 0, 0, 0);
      }
      __builtin_amdgcn_s_setprio(0);
      // ---- P = exp2(St); pack via cvt_pk + permlane32_swap; PV ----
      const u16* kt = tb + 8192;
#pragma unroll
      for (int kc = 0; kc < 2; ++kc) {
        float p0 = exp2f(st[8 * kc + 0]), p1 = exp2f(st[8 * kc + 1]);
        float p2 = exp2f(st[8 * kc + 2]), p3 = exp2f(st[8 * kc + 3]);
        float p4 = exp2f(st[8 * kc + 4]), p5 = exp2f(st[8 * kc + 5]);
        float p6 = exp2f(st[8 * kc + 6]), p7 = exp2f(st[8 * kc + 7]);
        lrow += ((p0 + p1) + (p2 + p3)) + ((p4 + p5) + (p6 + p7));
        uint32_t a0 = pk2(p0, p1), a1 = pk2(p2, p3);
        uint32_t b0 = pk2(p4, p5), b1 = pk2(p6, p7);
        asm("v_permlane32_swap_b32 %0, %1" : "+v"(a0), "+v"(b0));
        asm("v_permlane32_swap_b32 %0, %1" : "+v"(a1), "+v"(b1));
        union { short8 s; uint32_t u[4]; } pa;
        pa.u[0] = a0; pa.u[1] = a1; pa.u[2] = b0; pa.u[3] = b1;
        const int b16 = (kq * 4 + kc * 2 + hi) ^ (ln & 15);
        short8 v0 = *(const short8*)(kt + ln * 128 + (b16 << 3));
        short8 v1 = *(const short8*)(kt + (32 + ln) * 128 + (b16 << 3));
        __builtin_amdgcn_s_setprio(1);
        acc0 = __builtin_amdgcn_mfma_f32_32x32x16_bf16(pa.s, v0, acc0, 0, 0, 0);
        acc1 = __builtin_amdgcn_mfma_f32_32x32x16_bf16(pa.s, v1, acc1, 0, 0, 0);
        __builtin_amdgcn_s_setprio(0);
      }
    }

    __syncthreads();                       // all compute done; sTu free
    lrow += __shfl_xor(lrow, 32);

    // ---- symmetric dump: all 8 waves write their partials ----
    float* md = (float*)sTu;               // 8 regions x 8KB = 64KB
    float* my = md + (kq * 2 + qh) * 2048;
#pragma unroll
    for (int rr = 0; rr < 16; ++rr) {
      my[rr * 64 + l] = acc0[rr];
      my[(rr + 16) * 64 + l] = acc1[rr];
    }
    if (hi == 0) lb[kq * 2 + qh][ln] = lrow;
    __syncthreads();

    // ---- distributed merge: wave (kq,qh) handles rr in [4kq, 4kq+4) ----
#pragma unroll
    for (int i = 0; i < 4; ++i) {
      const int rr = 4 * kq + i;
      const int qq = i + 8 * kq + 4 * hi;
      const float o0 = md[qh * 2048 + rr * 64 + l] + md[(2 + qh) * 2048 + rr * 64 + l]
                     + md[(4 + qh) * 2048 + rr * 64 + l] + md[(6 + qh) * 2048 + rr * 64 + l];
      const float o1 = md[qh * 2048 + (rr + 16) * 64 + l] + md[(2 + qh) * 2048 + (rr + 16) * 64 + l]
                     + md[(4 + qh) * 2048 + (rr + 16) * 64 + l] + md[(6 + qh) * 2048 + (rr + 16) * 64 + l];
      const float lt = lb[qh][qq] + lb[2 + qh][qq] + lb[4 + qh][qq] + lb[6 + qh][qq];
      const float sc = 0.1f / lt;
      qst0[i] += o0 * sc;
      qst1[i] += o1 * sc;
    }

    if (step < 4) {
      __syncthreads();                     // all dump reads done; region 6 free
      u16* qsm = sTu + 24576 + qh * 2048;  // bytes [48K,56K), overlays region 6
#pragma unroll
      for (int i = 0; i < 4; ++i) {
        const int qq = i + 8 * kq + 4 * hi;
        qsm[qq * 64 + ((((ln >> 3)) ^ (qq & 7)) << 3) + (ln & 7)] = f2b(qst0[i]);
        qsm[qq * 64 + ((((ln >> 3) + 4) ^ (qq & 7)) << 3) + (ln & 7)] = f2b(qst1[i]);
      }
      __syncthreads();                     // qs16 visible to all waves
      const u16* qsr = sTu + 24576 + qh * 2048;
#pragma unroll
      for (int zc = 0; zc < 4; ++zc)
        qfrag[zc] = *(const short8*)(qsr + ln * 64 + (((zc * 2 + hi) ^ (ln & 7)) << 3));
      STAGE(0, 0);                         // writes bytes [0, 32K), no overlap
    } else {
#pragma unroll
      for (int i = 0; i < 4; ++i) {
        const int qq = i + 8 * kq + 4 * hi;
        const size_t base = (size_t)(q0w + qq) * DMODEL + h * HD;
        Qob[base + ln] = f2b(qst0[i]);
        Qob[base + 32 + ln] = f2b(qst1[i]);
      }
    }
  }
}

extern "C" void kernel_launch(void* const* d_in, const int* in_sizes, int n_in,
                              void* d_out, int out_size, void* d_ws, size_t ws_size,
                              hipStream_t stream) {
  const float* ctx = (const float*)d_in[0];
  const float* tgt = (const float*)d_in[1];
  const float* Wq  = (const float*)d_in[2];
  const float* Wk  = (const float*)d_in[3];
  const float* Wo  = (const float*)d_in[4];

  uint8_t* wp = (uint8_t*)d_ws;
  u16* ctxb = (u16*)wp; wp += (size_t)NCTX * DMODEL * 2;
  u16* tgtb = (u16*)wp; wp += (size_t)NTGT * DMODEL * 2;
  u16* wqb  = (u16*)wp; wp += (size_t)DMODEL * DMODEL * 2;
  u16* wkb  = (u16*)wp; wp += (size_t)DMODEL * DMODEL * 2;
  u16* wob  = (u16*)wp; wp += (size_t)DMODEL * DMODEL * 2;
  u16* Kbf  = (u16*)wp; wp += (size_t)NH * NCTX * HD * 2;
  u16* Ktb  = (u16*)wp; wp += (size_t)NH * HD * NCTX * 2;
  float* Qf = (float*)wp; wp += (size_t)NTGT * DMODEL * 4;
  u16* Qob  = (u16*)wp; wp += (size_t)NTGT * DMODEL * 2;

  // 1 launch: all five f32->bf16 conversions (counts in float4 units)
  hipLaunchKernelGGL(cvt_fused, dim3(2048), dim3(256), 0, stream,
                     ctx, ctxb, (int)((size_t)NCTX * DMODEL / 4),
                     tgt, tgtb, (int)((size_t)NTGT * DMODEL / 4),
                     Wq, wqb, (int)((size_t)DMODEL * DMODEL / 4),
                     Wk, wkb, (int)((size_t)DMODEL * DMODEL / 4),
                     Wo, wob, (int)((size_t)DMODEL * DMODEL / 4));
  // 1 launch: K projection (1024 blocks) + Q projection (512 blocks)
  hipLaunchKernelGGL(proj_kq, dim3((NCTX / 64) * (DMODEL / 64) + (NTGT / 64) * (DMODEL / 64)),
                     dim3(256), 0, stream, ctxb, wkb, tgtb, wqb, Kbf, Ktb, Qf);
  // 5-step energy attention
  hipLaunchKernelGGL(attn5, dim3(512), dim3(512), 0, stream, Kbf, Ktb, Qf, Qob);
  // Output projection: Qob x Wo^T -> d_out (f32)
  hipLaunchKernelGGL(gemm_c, dim3((NTGT / 64) * (DMODEL / 64)), dim3(256), 0, stream,
                     Qob, wob, (float*)d_out, NTGT, DMODEL, DMODEL);
}

// Round 19
// 336.113 us; speedup vs baseline: 1.6666x; 1.2897x over previous
//
#include <hip/hip_runtime.h>
#include <stdint.h>

typedef unsigned short u16;
typedef __attribute__((ext_vector_type(8))) short short8;
typedef __attribute__((ext_vector_type(4))) float f32x4;
typedef __attribute__((ext_vector_type(16))) float f32x16;

#define NCTX 4096
#define NTGT 2048
#define DMODEL 1024
#define NH 16
#define HD 64

typedef const __attribute__((address_space(1))) uint32_t g_u32;
typedef __attribute__((address_space(3))) uint32_t lds_u32;

__device__ inline u16 f2b(float f) {
  unsigned r;
  asm("v_cvt_pk_bf16_f32 %0, %1, %1" : "=v"(r) : "v"(f));
  return (u16)r;
}
__device__ inline uint32_t pk2(float lo, float hi_) {
  uint32_t r;
  asm("v_cvt_pk_bf16_f32 %0, %1, %2" : "=v"(r) : "v"(lo), "v"(hi_));
  return r;
}

// ---------------- fused f32 -> bf16 conversion (all 5 tensors, 1 launch) ----------------
__global__ void cvt_fused(const float* s0, u16* d0, int n0,
                          const float* s1, u16* d1, int n1,
                          const float* s2, u16* d2, int n2,
                          const float* s3, u16* d3, int n3,
                          const float* s4, u16* d4, int n4) {
  const int total = n0 + n1 + n2 + n3 + n4;
  for (int i = blockIdx.x * blockDim.x + threadIdx.x; i < total; i += gridDim.x * blockDim.x) {
    const float* s; u16* d; int j = i;
    if (j < n0) { s = s0; d = d0; }
    else if ((j -= n0) < n1) { s = s1; d = d1; }
    else if ((j -= n1) < n2) { s = s2; d = d2; }
    else if ((j -= n2) < n3) { s = s3; d = d3; }
    else { j -= n3; s = s4; d = d4; }
    const float4 v = ((const float4*)s)[j];
    ((uint2*)d)[j] = make_uint2(pk2(v.x, v.y), pk2(v.z, v.w));
  }
}

// ---------------- generic C = A * B^T body (bf16 in, f32 accum) ----------------
// B-tile staged in LDS via global_load_lds (inverse-swizzled source, XOR read),
// double-buffered, counted-vmcnt + raw barrier; A prefetched in registers.
// MODE 1: K-writer; Ck is pre-scaled by beta*log2e (used only for scores).
template<int MODE>
__device__ __forceinline__ void gemm_body(
    const u16* __restrict__ A, const u16* __restrict__ B,
    float* __restrict__ Cf, u16* __restrict__ Ck, u16* __restrict__ Ckt,
    int M, int N, int Kd, int bid, int tid, u16* sB) {
  const int bm = bid % (M >> 6);
  const int bn = bid / (M >> 6);
  const int w = tid >> 6, l = tid & 63;
  const int lg = l >> 4, lm = l & 15;
  const int m0 = (bm << 6) + (w << 4);
  const int n0 = bn << 6;

  const u16* Ar = A + (size_t)(m0 + lm) * Kd;
  // staging: wave w owns B rows [w*16, w*16+16); row r stores global 16B-block
  // (b ^ (r&7)) into LDS block b  (linear dest, pre-swizzled source)
  const int srow = l >> 3;                  // 0..7 within 8-row group
  const int sblk = ((l & 7) ^ srow) << 3;   // element offset of source block
  const u16* Bsrc = B + (size_t)(n0 + w * 16 + srow) * Kd + sblk;

  auto STAGE = [&](int buf, int kd) {
#pragma unroll
    for (int i = 0; i < 2; ++i)
      __builtin_amdgcn_global_load_lds((g_u32*)(Bsrc + (size_t)(i * 8) * Kd + kd),
          (lds_u32*)(sB + buf * 4096 + (w * 16 + i * 8) * 64), 16, 0, 0);
  };

  f32x4 acc[4] = {};
  short8 a0 = *(const short8*)(Ar + lg * 8);
  short8 a1 = *(const short8*)(Ar + 32 + lg * 8);
  STAGE(0, 0);

  for (int kd = 0; kd < Kd; kd += 64) {
    const int buf = (kd >> 6) & 1;
    asm volatile("s_waitcnt vmcnt(0)" ::: "memory");  // B-stage + A-prefetch done
    __builtin_amdgcn_s_barrier();                     // everyone's tile ready
    short8 na0, na1;
    if (kd + 64 < Kd) {
      STAGE(buf ^ 1, kd + 64);                        // prefetch next B-tile
      na0 = *(const short8*)(Ar + kd + 64 + lg * 8);  // prefetch next A-frags
      na1 = *(const short8*)(Ar + kd + 96 + lg * 8);
    }
    const u16* tb = sB + buf * 4096;
#pragma unroll
    for (int nf = 0; nf < 4; ++nf) {
      const int row = nf * 16 + lm;
      short8 b0 = *(const short8*)(tb + row * 64 + ((lg ^ (lm & 7)) << 3));
      short8 b1 = *(const short8*)(tb + row * 64 + (((lg + 4) ^ (lm & 7)) << 3));
      acc[nf] = __builtin_amdgcn_mfma_f32_16x16x32_bf16(a0, b0, acc[nf], 0, 0, 0);
      acc[nf] = __builtin_amdgcn_mfma_f32_16x16x32_bf16(a1, b1, acc[nf], 0, 0, 0);
    }
    if (kd + 64 < Kd) { a0 = na0; a1 = na1; }
  }

  if (MODE == 0) {
#pragma unroll
    for (int nf = 0; nf < 4; ++nf)
#pragma unroll
      for (int r = 0; r < 4; ++r)
        Cf[(size_t)(m0 + lg * 4 + r) * N + (n0 + nf * 16 + lm)] = acc[nf][r];
  } else {
    const float BL2E = 0.125f * 1.44269504088896340736f;
#pragma unroll
    for (int nf = 0; nf < 4; ++nf) {
      int n = n0 + nf * 16 + lm;
      int h = n >> 6, z = n & 63;
#pragma unroll
      for (int r = 0; r < 4; ++r) {
        int k = m0 + lg * 4 + r;
        Ck[((size_t)h * NCTX + k) * HD + z] = f2b(acc[nf][r] * BL2E);
        Ckt[((size_t)h * HD + z) * NCTX + k] = f2b(acc[nf][r]);
      }
    }
  }
}

// K-proj (blocks [0,1024)) + Q-proj (blocks [1024,1536)) in one dispatch.
__global__ __launch_bounds__(256) void proj_kq(
    const u16* __restrict__ ctxb, const u16* __restrict__ wkb,
    const u16* __restrict__ tgtb, const u16* __restrict__ wqb,
    u16* __restrict__ Kbf, u16* __restrict__ Ktb, float* __restrict__ Qf) {
  __shared__ __align__(16) u16 sB[2][4096];
  if (blockIdx.x < (NCTX / 64) * (DMODEL / 64))
    gemm_body<1>(ctxb, wkb, nullptr, Kbf, Ktb, NCTX, DMODEL, DMODEL,
                 blockIdx.x, threadIdx.x, &sB[0][0]);
  else
    gemm_body<0>(tgtb, wqb, Qf, nullptr, nullptr, NTGT, DMODEL, DMODEL,
                 blockIdx.x - (NCTX / 64) * (DMODEL / 64), threadIdx.x, &sB[0][0]);
}

__global__ __launch_bounds__(256) void gemm_c(
    const u16* __restrict__ A, const u16* __restrict__ B, float* __restrict__ Cf,
    int M, int N, int Kd) {
  __shared__ __align__(16) u16 sB[2][4096];
  gemm_body<0>(A, B, Cf, nullptr, nullptr, M, N, Kd, blockIdx.x, threadIdx.x, &sB[0][0]);
}

// ---------------- 5-step energy attention, 8-wave / 128-k tiles ----------------
// (unchanged from round 18 best: counted-vmcnt, distributed q-state, setprio)
__global__ __launch_bounds__(512, 4) void attn5(
    const u16* __restrict__ Kbf,   // [NH][NCTX][HD], pre-scaled by beta*log2e
    const u16* __restrict__ Ktb,   // [NH][HD][NCTX]
    const float* __restrict__ Qf,  // [NTGT][DMODEL]
    u16* __restrict__ Qob) {       // [NTGT][DMODEL] bf16
  __shared__ __align__(16) u16 sTu[32768];   // 64KB: 2x32KB tile buffers
  __shared__ float lb[8][32];                // 1KB: per-wave row-sum partials

  const int bid = blockIdx.x;
  const int h  = ((bid & 7) << 1) | ((bid >> 3) & 1);
  const int qt = bid >> 4;
  const int w = threadIdx.x >> 6, l = threadIdx.x & 63;
  const int ln = l & 31, hi = l >> 5;
  const int qh = w & 1, kq = w >> 1;
  const int q0w = qt * 64 + qh * 32;

  const u16* Kh  = Kbf + (size_t)h * NCTX * HD;
  const u16* Kth = Ktb + (size_t)h * HD * NCTX;

  auto STAGE = [&](int b, int t) {
#pragma unroll
    for (int i = 0; i < 2; ++i) {
      const u16* src = Kh + (size_t)(t * 128 + w * 16 + i * 8 + (l >> 3)) * HD
                          + (((l & 7) ^ (l >> 3) ^ ((w * 2 + i) & 7)) << 3);
      __builtin_amdgcn_global_load_lds((g_u32*)src,
          (lds_u32*)(sTu + b * 16384 + (w * 16 + i * 8) * 64), 16, 0, 0);
    }
#pragma unroll
    for (int i = 0; i < 2; ++i) {
      const u16* src = Kth + (size_t)(w * 8 + i * 4 + (l >> 4)) * NCTX + t * 128
                           + (((l & 15) ^ ((w * 8 + i * 4 + (l >> 4)) & 15)) << 3);
      __builtin_amdgcn_global_load_lds((g_u32*)src,
          (lds_u32*)(sTu + b * 16384 + 8192 + (w * 8 + i * 4) * 128), 16, 0, 0);
    }
  };

  // ---- Q B-frags: lane q=ln, z = zc*16 + 8*hi + e ----
  short8 qfrag[4];
  {
    const float* qp = Qf + (size_t)(q0w + ln) * DMODEL + h * HD + hi * 8;
#pragma unroll
    for (int zc = 0; zc < 4; ++zc) {
      float4 f0 = *(const float4*)(qp + zc * 16);
      float4 f1 = *(const float4*)(qp + zc * 16 + 4);
      union { short8 s; uint32_t u[4]; } t;
      t.u[0] = pk2(f0.x, f0.y); t.u[1] = pk2(f0.z, f0.w);
      t.u[2] = pk2(f1.x, f1.y); t.u[3] = pk2(f1.z, f1.w);
      qfrag[zc] = t.s;
    }
  }
  // ---- distributed q-state: rows qq = i + 8*kq + 4*hi, cols ln / 32+ln ----
  float qst0[4], qst1[4];
#pragma unroll
  for (int i = 0; i < 4; ++i) {
    const int qq = i + 8 * kq + 4 * hi;
    const float* qp = Qf + (size_t)(q0w + qq) * DMODEL + h * HD;
    qst0[i] = qp[ln];
    qst1[i] = qp[32 + ln];
  }

  STAGE(0, 0);

  for (int step = 0; step < 5; ++step) {
    f32x16 acc0 = {}, acc1 = {};
    float lrow = 0.f;

#pragma unroll 2
    for (int t = 0; t < 32; ++t) {
      const int buf = t & 1;
      asm volatile("s_waitcnt vmcnt(0)" ::: "memory");  // own tile-t loads done
      __builtin_amdgcn_s_barrier();                     // everyone's tile-t done
      if (t < 31) STAGE(buf ^ 1, t + 1);                // prefetch stays in flight
      const u16* tb = sTu + buf * 16384;

      // ---- St = K_strip * Q^T (k rows kq*32+ln, q cols = lanes) ----
      f32x16 st = {};
      __builtin_amdgcn_s_setprio(1);
#pragma unroll
      for (int zc = 0; zc < 4; ++zc) {
        const int b7 = (zc * 2 + hi) ^ (ln & 7) ^ ((kq * 4 + (ln >> 3)) & 7);
        short8 kf = *(const short8*)(tb + (kq * 32 + ln) * 64 + (b7 << 3));
        st = __builtin_amdgcn_mfma_f32_32x32x16_bf16(kf, qfrag[zc], st, 0, 0, 0);
      }
      __builtin_amdgcn_s_setprio(0);
      // ---- P = exp2(St); pack via cvt_pk + permlane32_swap; PV ----
      const u16* kt = tb + 8192;
#pragma unroll
      for (int kc = 0; kc < 2; ++kc) {
        float p0 = exp2f(st[8 * kc + 0]), p1 = exp2f(st[8 * kc + 1]);
        float p2 = exp2f(st[8 * kc + 2]), p3 = exp2f(st[8 * kc + 3]);
        float p4 = exp2f(st[8 * kc + 4]), p5 = exp2f(st[8 * kc + 5]);
        float p6 = exp2f(st[8 * kc + 6]), p7 = exp2f(st[8 * kc + 7]);
        lrow += ((p0 + p1) + (p2 + p3)) + ((p4 + p5) + (p6 + p7));
        uint32_t a0 = pk2(p0, p1), a1 = pk2(p2, p3);
        uint32_t b0 = pk2(p4, p5), b1 = pk2(p6, p7);
        asm("v_permlane32_swap_b32 %0, %1" : "+v"(a0), "+v"(b0));
        asm("v_permlane32_swap_b32 %0, %1" : "+v"(a1), "+v"(b1));
        union { short8 s; uint32_t u[4]; } pa;
        pa.u[0] = a0; pa.u[1] = a1; pa.u[2] = b0; pa.u[3] = b1;
        const int b16 = (kq * 4 + kc * 2 + hi) ^ (ln & 15);
        short8 v0 = *(const short8*)(kt + ln * 128 + (b16 << 3));
        short8 v1 = *(const short8*)(kt + (32 + ln) * 128 + (b16 << 3));
        __builtin_amdgcn_s_setprio(1);
        acc0 = __builtin_amdgcn_mfma_f32_32x32x16_bf16(pa.s, v0, acc0, 0, 0, 0);
        acc1 = __builtin_amdgcn_mfma_f32_32x32x16_bf16(pa.s, v1, acc1, 0, 0, 0);
        __builtin_amdgcn_s_setprio(0);
      }
    }

    __syncthreads();                       // all compute done; sTu free
    lrow += __shfl_xor(lrow, 32);

    // ---- symmetric dump: all 8 waves write their partials ----
    float* md = (float*)sTu;               // 8 regions x 8KB = 64KB
    float* my = md + (kq * 2 + qh) * 2048;
#pragma unroll
    for (int rr = 0; rr < 16; ++rr) {
      my[rr * 64 + l] = acc0[rr];
      my[(rr + 16) * 64 + l] = acc1[rr];
    }
    if (hi == 0) lb[kq * 2 + qh][ln] = lrow;
    __syncthreads();

    // ---- distributed merge: wave (kq,qh) handles rr in [4kq, 4kq+4) ----
#pragma unroll
    for (int i = 0; i < 4; ++i) {
      const int rr = 4 * kq + i;
      const int qq = i + 8 * kq + 4 * hi;
      const float o0 = md[qh * 2048 + rr * 64 + l] + md[(2 + qh) * 2048 + rr * 64 + l]
                     + md[(4 + qh) * 2048 + rr * 64 + l] + md[(6 + qh) * 2048 + rr * 64 + l];
      const float o1 = md[qh * 2048 + (rr + 16) * 64 + l] + md[(2 + qh) * 2048 + (rr + 16) * 64 + l]
                     + md[(4 + qh) * 2048 + (rr + 16) * 64 + l] + md[(6 + qh) * 2048 + (rr + 16) * 64 + l];
      const float lt = lb[qh][qq] + lb[2 + qh][qq] + lb[4 + qh][qq] + lb[6 + qh][qq];
      const float sc = 0.1f / lt;
      qst0[i] += o0 * sc;
      qst1[i] += o1 * sc;
    }

    if (step < 4) {
      __syncthreads();                     // all dump reads done; region 6 free
      u16* qsm = sTu + 24576 + qh * 2048;  // bytes [48K,56K), overlays region 6
#pragma unroll
      for (int i = 0; i < 4; ++i) {
        const int qq = i + 8 * kq + 4 * hi;
        qsm[qq * 64 + ((((ln >> 3)) ^ (qq & 7)) << 3) + (ln & 7)] = f2b(qst0[i]);
        qsm[qq * 64 + ((((ln >> 3) + 4) ^ (qq & 7)) << 3) + (ln & 7)] = f2b(qst1[i]);
      }
      __syncthreads();                     // qs16 visible to all waves
      const u16* qsr = sTu + 24576 + qh * 2048;
#pragma unroll
      for (int zc = 0; zc < 4; ++zc)
        qfrag[zc] = *(const short8*)(qsr + ln * 64 + (((zc * 2 + hi) ^ (ln & 7)) << 3));
      STAGE(0, 0);                         // writes bytes [0, 32K), no overlap
    } else {
#pragma unroll
      for (int i = 0; i < 4; ++i) {
        const int qq = i + 8 * kq + 4 * hi;
        const size_t base = (size_t)(q0w + qq) * DMODEL + h * HD;
        Qob[base + ln] = f2b(qst0[i]);
        Qob[base + 32 + ln] = f2b(qst1[i]);
      }
    }
  }
}

extern "C" void kernel_launch(void* const* d_in, const int* in_sizes, int n_in,
                              void* d_out, int out_size, void* d_ws, size_t ws_size,
                              hipStream_t stream) {
  const float* ctx = (const float*)d_in[0];
  const float* tgt = (const float*)d_in[1];
  const float* Wq  = (const float*)d_in[2];
  const float* Wk  = (const float*)d_in[3];
  const float* Wo  = (const float*)d_in[4];

  uint8_t* wp = (uint8_t*)d_ws;
  u16* ctxb = (u16*)wp; wp += (size_t)NCTX * DMODEL * 2;
  u16* tgtb = (u16*)wp; wp += (size_t)NTGT * DMODEL * 2;
  u16* wqb  = (u16*)wp; wp += (size_t)DMODEL * DMODEL * 2;
  u16* wkb  = (u16*)wp; wp += (size_t)DMODEL * DMODEL * 2;
  u16* wob  = (u16*)wp; wp += (size_t)DMODEL * DMODEL * 2;
  u16* Kbf  = (u16*)wp; wp += (size_t)NH * NCTX * HD * 2;
  u16* Ktb  = (u16*)wp; wp += (size_t)NH * HD * NCTX * 2;
  float* Qf = (float*)wp; wp += (size_t)NTGT * DMODEL * 4;
  u16* Qob  = (u16*)wp; wp += (size_t)NTGT * DMODEL * 2;

  // 1 launch: all five f32->bf16 conversions (counts in float4 units)
  hipLaunchKernelGGL(cvt_fused, dim3(2048), dim3(256), 0, stream,
                     ctx, ctxb, (int)((size_t)NCTX * DMODEL / 4),
                     tgt, tgtb, (int)((size_t)NTGT * DMODEL / 4),
                     Wq, wqb, (int)((size_t)DMODEL * DMODEL / 4),
                     Wk, wkb, (int)((size_t)DMODEL * DMODEL / 4),
                     Wo, wob, (int)((size_t)DMODEL * DMODEL / 4));
  // 1 launch: K projection (1024 blocks) + Q projection (512 blocks)
  hipLaunchKernelGGL(proj_kq, dim3((NCTX / 64) * (DMODEL / 64) + (NTGT / 64) * (DMODEL / 64)),
                     dim3(256), 0, stream, ctxb, wkb, tgtb, wqb, Kbf, Ktb, Qf);
  // 5-step energy attention
  hipLaunchKernelGGL(attn5, dim3(512), dim3(512), 0, stream, Kbf, Ktb, Qf, Qob);
  // Output projection: Qob x Wo^T -> d_out (f32)
  hipLaunchKernelGGL(gemm_c, dim3((NTGT / 64) * (DMODEL / 64)), dim3(256), 0, stream,
                     Qob, wob, (float*)d_out, NTGT, DMODEL, DMODEL);
}

// Round 20
// 333.343 us; speedup vs baseline: 1.6804x; 1.0083x over previous
//
#include <hip/hip_runtime.h>
#include <stdint.h>

typedef unsigned short u16;
typedef __attribute__((ext_vector_type(8))) short short8;
typedef __attribute__((ext_vector_type(4))) float f32x4;
typedef __attribute__((ext_vector_type(16))) float f32x16;

#define NCTX 4096
#define NTGT 2048
#define DMODEL 1024
#define NH 16
#define HD 64

typedef const __attribute__((address_space(1))) uint32_t g_u32;
typedef __attribute__((address_space(3))) uint32_t lds_u32;

__device__ inline u16 f2b(float f) {
  unsigned r;
  asm("v_cvt_pk_bf16_f32 %0, %1, %1" : "=v"(r) : "v"(f));
  return (u16)r;
}
__device__ inline uint32_t pk2(float lo, float hi_) {
  uint32_t r;
  asm("v_cvt_pk_bf16_f32 %0, %1, %2" : "=v"(r) : "v"(lo), "v"(hi_));
  return r;
}

// ---------------- fused f32 -> bf16 conversion (all 5 tensors, 1 launch) ----------------
__global__ void cvt_fused(const float* s0, u16* d0, int n0,
                          const float* s1, u16* d1, int n1,
                          const float* s2, u16* d2, int n2,
                          const float* s3, u16* d3, int n3,
                          const float* s4, u16* d4, int n4) {
  const int total = n0 + n1 + n2 + n3 + n4;
  for (int i = blockIdx.x * blockDim.x + threadIdx.x; i < total; i += gridDim.x * blockDim.x) {
    const float* s; u16* d; int j = i;
    if (j < n0) { s = s0; d = d0; }
    else if ((j -= n0) < n1) { s = s1; d = d1; }
    else if ((j -= n1) < n2) { s = s2; d = d2; }
    else if ((j -= n2) < n3) { s = s3; d = d3; }
    else { j -= n3; s = s4; d = d4; }
    const float4 v = ((const float4*)s)[j];
    ((uint2*)d)[j] = make_uint2(pk2(v.x, v.y), pk2(v.z, v.w));
  }
}

// ---------------- generic C = A * B^T body (bf16 in, f32 accum) ----------------
// B-tile staged in LDS via global_load_lds (inverse-swizzled source, XOR read),
// double-buffered, counted-vmcnt + raw barrier; A prefetched in registers.
// MODE 1: K-writer; Ck is pre-scaled by beta*log2e (used only for scores).
template<int MODE>
__device__ __forceinline__ void gemm_body(
    const u16* __restrict__ A, const u16* __restrict__ B,
    float* __restrict__ Cf, u16* __restrict__ Ck, u16* __restrict__ Ckt,
    int M, int N, int Kd, int bid, int tid, u16* sB) {
  const int bm = bid % (M >> 6);
  const int bn = bid / (M >> 6);
  const int w = tid >> 6, l = tid & 63;
  const int lg = l >> 4, lm = l & 15;
  const int m0 = (bm << 6) + (w << 4);
  const int n0 = bn << 6;

  const u16* Ar = A + (size_t)(m0 + lm) * Kd;
  const int srow = l >> 3;                  // 0..7 within 8-row group
  const int sblk = ((l & 7) ^ srow) << 3;   // element offset of source block
  const u16* Bsrc = B + (size_t)(n0 + w * 16 + srow) * Kd + sblk;

  auto STAGE = [&](int buf, int kd) {
#pragma unroll
    for (int i = 0; i < 2; ++i)
      __builtin_amdgcn_global_load_lds((g_u32*)(Bsrc + (size_t)(i * 8) * Kd + kd),
          (lds_u32*)(sB + buf * 4096 + (w * 16 + i * 8) * 64), 16, 0, 0);
  };

  f32x4 acc[4] = {};
  short8 a0 = *(const short8*)(Ar + lg * 8);
  short8 a1 = *(const short8*)(Ar + 32 + lg * 8);
  STAGE(0, 0);

  for (int kd = 0; kd < Kd; kd += 64) {
    const int buf = (kd >> 6) & 1;
    asm volatile("s_waitcnt vmcnt(0)" ::: "memory");  // B-stage + A-prefetch done
    __builtin_amdgcn_s_barrier();                     // everyone's tile ready
    short8 na0, na1;
    if (kd + 64 < Kd) {
      STAGE(buf ^ 1, kd + 64);                        // prefetch next B-tile
      na0 = *(const short8*)(Ar + kd + 64 + lg * 8);  // prefetch next A-frags
      na1 = *(const short8*)(Ar + kd + 96 + lg * 8);
    }
    const u16* tb = sB + buf * 4096;
#pragma unroll
    for (int nf = 0; nf < 4; ++nf) {
      const int row = nf * 16 + lm;
      short8 b0 = *(const short8*)(tb + row * 64 + ((lg ^ (lm & 7)) << 3));
      short8 b1 = *(const short8*)(tb + row * 64 + (((lg + 4) ^ (lm & 7)) << 3));
      acc[nf] = __builtin_amdgcn_mfma_f32_16x16x32_bf16(a0, b0, acc[nf], 0, 0, 0);
      acc[nf] = __builtin_amdgcn_mfma_f32_16x16x32_bf16(a1, b1, acc[nf], 0, 0, 0);
    }
    if (kd + 64 < Kd) { a0 = na0; a1 = na1; }
  }

  if (MODE == 0) {
#pragma unroll
    for (int nf = 0; nf < 4; ++nf)
#pragma unroll
      for (int r = 0; r < 4; ++r)
        Cf[(size_t)(m0 + lg * 4 + r) * N + (n0 + nf * 16 + lm)] = acc[nf][r];
  } else {
    const float BL2E = 0.125f * 1.44269504088896340736f;
#pragma unroll
    for (int nf = 0; nf < 4; ++nf) {
      int n = n0 + nf * 16 + lm;
      int h = n >> 6, z = n & 63;
#pragma unroll
      for (int r = 0; r < 4; ++r) {
        int k = m0 + lg * 4 + r;
        Ck[((size_t)h * NCTX + k) * HD + z] = f2b(acc[nf][r] * BL2E);
        Ckt[((size_t)h * HD + z) * NCTX + k] = f2b(acc[nf][r]);
      }
    }
  }
}

// K-proj (blocks [0,1024)) + Q-proj (blocks [1024,1536)) in one dispatch.
__global__ __launch_bounds__(256) void proj_kq(
    const u16* __restrict__ ctxb, const u16* __restrict__ wkb,
    const u16* __restrict__ tgtb, const u16* __restrict__ wqb,
    u16* __restrict__ Kbf, u16* __restrict__ Ktb, float* __restrict__ Qf) {
  __shared__ __align__(16) u16 sB[2][4096];
  if (blockIdx.x < (NCTX / 64) * (DMODEL / 64))
    gemm_body<1>(ctxb, wkb, nullptr, Kbf, Ktb, NCTX, DMODEL, DMODEL,
                 blockIdx.x, threadIdx.x, &sB[0][0]);
  else
    gemm_body<0>(tgtb, wqb, Qf, nullptr, nullptr, NTGT, DMODEL, DMODEL,
                 blockIdx.x - (NCTX / 64) * (DMODEL / 64), threadIdx.x, &sB[0][0]);
}

__global__ __launch_bounds__(256) void gemm_c(
    const u16* __restrict__ A, const u16* __restrict__ B, float* __restrict__ Cf,
    int M, int N, int Kd) {
  __shared__ __align__(16) u16 sB[2][4096];
  gemm_body<0>(A, B, Cf, nullptr, nullptr, M, N, Kd, blockIdx.x, threadIdx.x, &sB[0][0]);
}

// ---------------- 5-step energy attention, 8-wave / 128-k tiles ----------------
// Round-18 structure + packed-f32 lrow accumulation (v_pk_add_f32 diet).
__global__ __launch_bounds__(512, 4) void attn5(
    const u16* __restrict__ Kbf,   // [NH][NCTX][HD], pre-scaled by beta*log2e
    const u16* __restrict__ Ktb,   // [NH][HD][NCTX]
    const float* __restrict__ Qf,  // [NTGT][DMODEL]
    u16* __restrict__ Qob) {       // [NTGT][DMODEL] bf16
  __shared__ __align__(16) u16 sTu[32768];   // 64KB: 2x32KB tile buffers
  __shared__ float lb[8][32];                // 1KB: per-wave row-sum partials

  const int bid = blockIdx.x;
  const int h  = ((bid & 7) << 1) | ((bid >> 3) & 1);
  const int qt = bid >> 4;
  const int w = threadIdx.x >> 6, l = threadIdx.x & 63;
  const int ln = l & 31, hi = l >> 5;
  const int qh = w & 1, kq = w >> 1;
  const int q0w = qt * 64 + qh * 32;

  const u16* Kh  = Kbf + (size_t)h * NCTX * HD;
  const u16* Kth = Ktb + (size_t)h * HD * NCTX;

  auto STAGE = [&](int b, int t) {
#pragma unroll
    for (int i = 0; i < 2; ++i) {
      const u16* src = Kh + (size_t)(t * 128 + w * 16 + i * 8 + (l >> 3)) * HD
                          + (((l & 7) ^ (l >> 3) ^ ((w * 2 + i) & 7)) << 3);
      __builtin_amdgcn_global_load_lds((g_u32*)src,
          (lds_u32*)(sTu + b * 16384 + (w * 16 + i * 8) * 64), 16, 0, 0);
    }
#pragma unroll
    for (int i = 0; i < 2; ++i) {
      const u16* src = Kth + (size_t)(w * 8 + i * 4 + (l >> 4)) * NCTX + t * 128
                           + (((l & 15) ^ ((w * 8 + i * 4 + (l >> 4)) & 15)) << 3);
      __builtin_amdgcn_global_load_lds((g_u32*)src,
          (lds_u32*)(sTu + b * 16384 + 8192 + (w * 8 + i * 4) * 128), 16, 0, 0);
    }
  };

  // ---- Q B-frags: lane q=ln, z = zc*16 + 8*hi + e ----
  short8 qfrag[4];
  {
    const float* qp = Qf + (size_t)(q0w + ln) * DMODEL + h * HD + hi * 8;
#pragma unroll
    for (int zc = 0; zc < 4; ++zc) {
      float4 f0 = *(const float4*)(qp + zc * 16);
      float4 f1 = *(const float4*)(qp + zc * 16 + 4);
      union { short8 s; uint32_t u[4]; } t;
      t.u[0] = pk2(f0.x, f0.y); t.u[1] = pk2(f0.z, f0.w);
      t.u[2] = pk2(f1.x, f1.y); t.u[3] = pk2(f1.z, f1.w);
      qfrag[zc] = t.s;
    }
  }
  // ---- distributed q-state: rows qq = i + 8*kq + 4*hi, cols ln / 32+ln ----
  float qst0[4], qst1[4];
#pragma unroll
  for (int i = 0; i < 4; ++i) {
    const int qq = i + 8 * kq + 4 * hi;
    const float* qp = Qf + (size_t)(q0w + qq) * DMODEL + h * HD;
    qst0[i] = qp[ln];
    qst1[i] = qp[32 + ln];
  }

  STAGE(0, 0);

  for (int step = 0; step < 5; ++step) {
    f32x16 acc0 = {}, acc1 = {};
    float2 lrow2 = make_float2(0.f, 0.f);   // packed row-sum (v_pk_add_f32)

#pragma unroll 2
    for (int t = 0; t < 32; ++t) {
      const int buf = t & 1;
      asm volatile("s_waitcnt vmcnt(0)" ::: "memory");  // own tile-t loads done
      __builtin_amdgcn_s_barrier();                     // everyone's tile-t done
      if (t < 31) STAGE(buf ^ 1, t + 1);                // prefetch stays in flight
      const u16* tb = sTu + buf * 16384;

      // ---- St = K_strip * Q^T (k rows kq*32+ln, q cols = lanes) ----
      f32x16 st = {};
      __builtin_amdgcn_s_setprio(1);
#pragma unroll
      for (int zc = 0; zc < 4; ++zc) {
        const int b7 = (zc * 2 + hi) ^ (ln & 7) ^ ((kq * 4 + (ln >> 3)) & 7);
        short8 kf = *(const short8*)(tb + (kq * 32 + ln) * 64 + (b7 << 3));
        st = __builtin_amdgcn_mfma_f32_32x32x16_bf16(kf, qfrag[zc], st, 0, 0, 0);
      }
      __builtin_amdgcn_s_setprio(0);
      // ---- P = exp2(St); pack via cvt_pk + permlane32_swap; PV ----
      const u16* kt = tb + 8192;
#pragma unroll
      for (int kc = 0; kc < 2; ++kc) {
        float p0 = exp2f(st[8 * kc + 0]), p1 = exp2f(st[8 * kc + 1]);
        float p2 = exp2f(st[8 * kc + 2]), p3 = exp2f(st[8 * kc + 3]);
        float p4 = exp2f(st[8 * kc + 4]), p5 = exp2f(st[8 * kc + 5]);
        float p6 = exp2f(st[8 * kc + 6]), p7 = exp2f(st[8 * kc + 7]);
        // packed accumulation: 3 float2 adds + 1 float2 acc add per kc
        float2 s01 = make_float2(p0 + p4, p1 + p5);
        float2 s23 = make_float2(p2 + p6, p3 + p7);
        lrow2.x += s01.x + s23.x;
        lrow2.y += s01.y + s23.y;
        uint32_t a0 = pk2(p0, p1), a1 = pk2(p2, p3);
        uint32_t b0 = pk2(p4, p5), b1 = pk2(p6, p7);
        asm("v_permlane32_swap_b32 %0, %1" : "+v"(a0), "+v"(b0));
        asm("v_permlane32_swap_b32 %0, %1" : "+v"(a1), "+v"(b1));
        union { short8 s; uint32_t u[4]; } pa;
        pa.u[0] = a0; pa.u[1] = a1; pa.u[2] = b0; pa.u[3] = b1;
        const int b16 = (kq * 4 + kc * 2 + hi) ^ (ln & 15);
        short8 v0 = *(const short8*)(kt + ln * 128 + (b16 << 3));
        short8 v1 = *(const short8*)(kt + (32 + ln) * 128 + (b16 << 3));
        __builtin_amdgcn_s_setprio(1);
        acc0 = __builtin_amdgcn_mfma_f32_32x32x16_bf16(pa.s, v0, acc0, 0, 0, 0);
        acc1 = __builtin_amdgcn_mfma_f32_32x32x16_bf16(pa.s, v1, acc1, 0, 0, 0);
        __builtin_amdgcn_s_setprio(0);
      }
    }

    __syncthreads();                       // all compute done; sTu free
    float lrow = lrow2.x + lrow2.y;
    lrow += __shfl_xor(lrow, 32);

    // ---- symmetric dump: all 8 waves write their partials ----
    float* md = (float*)sTu;               // 8 regions x 8KB = 64KB
    float* my = md + (kq * 2 + qh) * 2048;
#pragma unroll
    for (int rr = 0; rr < 16; ++rr) {
      my[rr * 64 + l] = acc0[rr];
      my[(rr + 16) * 64 + l] = acc1[rr];
    }
    if (hi == 0) lb[kq * 2 + qh][ln] = lrow;
    __syncthreads();

    // ---- distributed merge: wave (kq,qh) handles rr in [4kq, 4kq+4) ----
#pragma unroll
    for (int i = 0; i < 4; ++i) {
      const int rr = 4 * kq + i;
      const int qq = i + 8 * kq + 4 * hi;
      const float o0 = md[qh * 2048 + rr * 64 + l] + md[(2 + qh) * 2048 + rr * 64 + l]
                     + md[(4 + qh) * 2048 + rr * 64 + l] + md[(6 + qh) * 2048 + rr * 64 + l];
      const float o1 = md[qh * 2048 + (rr + 16) * 64 + l] + md[(2 + qh) * 2048 + (rr + 16) * 64 + l]
                     + md[(4 + qh) * 2048 + (rr + 16) * 64 + l] + md[(6 + qh) * 2048 + (rr + 16) * 64 + l];
      const float lt = lb[qh][qq] + lb[2 + qh][qq] + lb[4 + qh][qq] + lb[6 + qh][qq];
      const float sc = 0.1f / lt;
      qst0[i] += o0 * sc;
      qst1[i] += o1 * sc;
    }

    if (step < 4) {
      __syncthreads();                     // all dump reads done; region 6 free
      u16* qsm = sTu + 24576 + qh * 2048;  // bytes [48K,56K), overlays region 6
#pragma unroll
      for (int i = 0; i < 4; ++i) {
        const int qq = i + 8 * kq + 4 * hi;
        qsm[qq * 64 + ((((ln >> 3)) ^ (qq & 7)) << 3) + (ln & 7)] = f2b(qst0[i]);
        qsm[qq * 64 + ((((ln >> 3) + 4) ^ (qq & 7)) << 3) + (ln & 7)] = f2b(qst1[i]);
      }
      __syncthreads();                     // qs16 visible to all waves
      const u16* qsr = sTu + 24576 + qh * 2048;
#pragma unroll
      for (int zc = 0; zc < 4; ++zc)
        qfrag[zc] = *(const short8*)(qsr + ln * 64 + (((zc * 2 + hi) ^ (ln & 7)) << 3));
      STAGE(0, 0);                         // writes bytes [0, 32K), no overlap
    } else {
#pragma unroll
      for (int i = 0; i < 4; ++i) {
        const int qq = i + 8 * kq + 4 * hi;
        const size_t base = (size_t)(q0w + qq) * DMODEL + h * HD;
        Qob[base + ln] = f2b(qst0[i]);
        Qob[base + 32 + ln] = f2b(qst1[i]);
      }
    }
  }
}

extern "C" void kernel_launch(void* const* d_in, const int* in_sizes, int n_in,
                              void* d_out, int out_size, void* d_ws, size_t ws_size,
                              hipStream_t stream) {
  const float* ctx = (const float*)d_in[0];
  const float* tgt = (const float*)d_in[1];
  const float* Wq  = (const float*)d_in[2];
  const float* Wk  = (const float*)d_in[3];
  const float* Wo  = (const float*)d_in[4];

  uint8_t* wp = (uint8_t*)d_ws;
  u16* ctxb = (u16*)wp; wp += (size_t)NCTX * DMODEL * 2;
  u16* tgtb = (u16*)wp; wp += (size_t)NTGT * DMODEL * 2;
  u16* wqb  = (u16*)wp; wp += (size_t)DMODEL * DMODEL * 2;
  u16* wkb  = (u16*)wp; wp += (size_t)DMODEL * DMODEL * 2;
  u16* wob  = (u16*)wp; wp += (size_t)DMODEL * DMODEL * 2;
  u16* Kbf  = (u16*)wp; wp += (size_t)NH * NCTX * HD * 2;
  u16* Ktb  = (u16*)wp; wp += (size_t)NH * HD * NCTX * 2;
  float* Qf = (float*)wp; wp += (size_t)NTGT * DMODEL * 4;
  u16* Qob  = (u16*)wp; wp += (size_t)NTGT * DMODEL * 2;

  // 1 launch: all five f32->bf16 conversions (counts in float4 units)
  hipLaunchKernelGGL(cvt_fused, dim3(2048), dim3(256), 0, stream,
                     ctx, ctxb, (int)((size_t)NCTX * DMODEL / 4),
                     tgt, tgtb, (int)((size_t)NTGT * DMODEL / 4),
                     Wq, wqb, (int)((size_t)DMODEL * DMODEL / 4),
                     Wk, wkb, (int)((size_t)DMODEL * DMODEL / 4),
                     Wo, wob, (int)((size_t)DMODEL * DMODEL / 4));
  // 1 launch: K projection (1024 blocks) + Q projection (512 blocks)
  hipLaunchKernelGGL(proj_kq, dim3((NCTX / 64) * (DMODEL / 64) + (NTGT / 64) * (DMODEL / 64)),
                     dim3(256), 0, stream, ctxb, wkb, tgtb, wqb, Kbf, Ktb, Qf);
  // 5-step energy attention
  hipLaunchKernelGGL(attn5, dim3(512), dim3(512), 0, stream, Kbf, Ktb, Qf, Qob);
  // Output projection: Qob x Wo^T -> d_out (f32)
  hipLaunchKernelGGL(gemm_c, dim3((NTGT / 64) * (DMODEL / 64)), dim3(256), 0, stream,
                     Qob, wob, (float*)d_out, NTGT, DMODEL, DMODEL);
}

// Round 21
// 274.243 us; speedup vs baseline: 2.0425x; 1.2155x over previous
//
#include <hip/hip_runtime.h>
#include <stdint.h>

typedef unsigned short u16;
typedef __attribute__((ext_vector_type(8))) short short8;
typedef __attribute__((ext_vector_type(4))) float f32x4;
typedef __attribute__((ext_vector_type(16))) float f32x16;

#define NCTX 4096
#define NTGT 2048
#define DMODEL 1024
#define NH 16
#define HD 64

typedef const __attribute__((address_space(1))) uint32_t g_u32;
typedef __attribute__((address_space(3))) uint32_t lds_u32;

__device__ inline u16 f2b(float f) {
  unsigned r;
  asm("v_cvt_pk_bf16_f32 %0, %1, %1" : "=v"(r) : "v"(f));
  return (u16)r;
}
__device__ inline uint32_t pk2(float lo, float hi_) {
  uint32_t r;
  asm("v_cvt_pk_bf16_f32 %0, %1, %2" : "=v"(r) : "v"(lo), "v"(hi_));
  return r;
}
// raw hardware exp2 — args bounded |x|<=~7.2, denormal fixup not needed
__device__ inline float ex2(float x) {
  float r;
  asm("v_exp_f32 %0, %1" : "=v"(r) : "v"(x));
  return r;
}

// ---------------- fused f32 -> bf16 conversion (all 5 tensors, 1 launch) ----------------
__global__ void cvt_fused(const float* s0, u16* d0, int n0,
                          const float* s1, u16* d1, int n1,
                          const float* s2, u16* d2, int n2,
                          const float* s3, u16* d3, int n3,
                          const float* s4, u16* d4, int n4) {
  const int total = n0 + n1 + n2 + n3 + n4;
  for (int i = blockIdx.x * blockDim.x + threadIdx.x; i < total; i += gridDim.x * blockDim.x) {
    const float* s; u16* d; int j = i;
    if (j < n0) { s = s0; d = d0; }
    else if ((j -= n0) < n1) { s = s1; d = d1; }
    else if ((j -= n1) < n2) { s = s2; d = d2; }
    else if ((j -= n2) < n3) { s = s3; d = d3; }
    else { j -= n3; s = s4; d = d4; }
    const float4 v = ((const float4*)s)[j];
    ((uint2*)d)[j] = make_uint2(pk2(v.x, v.y), pk2(v.z, v.w));
  }
}

// ---------------- generic C = A * B^T body (bf16 in, f32 accum) ----------------
// B-tile staged in LDS via global_load_lds (inverse-swizzled source, XOR read),
// double-buffered, counted-vmcnt + raw barrier; A prefetched in registers.
// MODE 1: K-writer; Ck is pre-scaled by beta*log2e (used only for scores).
template<int MODE>
__device__ __forceinline__ void gemm_body(
    const u16* __restrict__ A, const u16* __restrict__ B,
    float* __restrict__ Cf, u16* __restrict__ Ck, u16* __restrict__ Ckt,
    int M, int N, int Kd, int bid, int tid, u16* sB) {
  const int bm = bid % (M >> 6);
  const int bn = bid / (M >> 6);
  const int w = tid >> 6, l = tid & 63;
  const int lg = l >> 4, lm = l & 15;
  const int m0 = (bm << 6) + (w << 4);
  const int n0 = bn << 6;

  const u16* Ar = A + (size_t)(m0 + lm) * Kd;
  const int srow = l >> 3;                  // 0..7 within 8-row group
  const int sblk = ((l & 7) ^ srow) << 3;   // element offset of source block
  const u16* Bsrc = B + (size_t)(n0 + w * 16 + srow) * Kd + sblk;

  auto STAGE = [&](int buf, int kd) {
#pragma unroll
    for (int i = 0; i < 2; ++i)
      __builtin_amdgcn_global_load_lds((g_u32*)(Bsrc + (size_t)(i * 8) * Kd + kd),
          (lds_u32*)(sB + buf * 4096 + (w * 16 + i * 8) * 64), 16, 0, 0);
  };

  f32x4 acc[4] = {};
  short8 a0 = *(const short8*)(Ar + lg * 8);
  short8 a1 = *(const short8*)(Ar + 32 + lg * 8);
  STAGE(0, 0);

  for (int kd = 0; kd < Kd; kd += 64) {
    const int buf = (kd >> 6) & 1;
    asm volatile("s_waitcnt vmcnt(0)" ::: "memory");  // B-stage + A-prefetch done
    __builtin_amdgcn_s_barrier();                     // everyone's tile ready
    short8 na0, na1;
    if (kd + 64 < Kd) {
      STAGE(buf ^ 1, kd + 64);                        // prefetch next B-tile
      na0 = *(const short8*)(Ar + kd + 64 + lg * 8);  // prefetch next A-frags
      na1 = *(const short8*)(Ar + kd + 96 + lg * 8);
    }
    const u16* tb = sB + buf * 4096;
#pragma unroll
    for (int nf = 0; nf < 4; ++nf) {
      const int row = nf * 16 + lm;
      short8 b0 = *(const short8*)(tb + row * 64 + ((lg ^ (lm & 7)) << 3));
      short8 b1 = *(const short8*)(tb + row * 64 + (((lg + 4) ^ (lm & 7)) << 3));
      acc[nf] = __builtin_amdgcn_mfma_f32_16x16x32_bf16(a0, b0, acc[nf], 0, 0, 0);
      acc[nf] = __builtin_amdgcn_mfma_f32_16x16x32_bf16(a1, b1, acc[nf], 0, 0, 0);
    }
    if (kd + 64 < Kd) { a0 = na0; a1 = na1; }
  }

  if (MODE == 0) {
#pragma unroll
    for (int nf = 0; nf < 4; ++nf)
#pragma unroll
      for (int r = 0; r < 4; ++r)
        Cf[(size_t)(m0 + lg * 4 + r) * N + (n0 + nf * 16 + lm)] = acc[nf][r];
  } else {
    const float BL2E = 0.125f * 1.44269504088896340736f;
#pragma unroll
    for (int nf = 0; nf < 4; ++nf) {
      int n = n0 + nf * 16 + lm;
      int h = n >> 6, z = n & 63;
#pragma unroll
      for (int r = 0; r < 4; ++r) {
        int k = m0 + lg * 4 + r;
        Ck[((size_t)h * NCTX + k) * HD + z] = f2b(acc[nf][r] * BL2E);
        Ckt[((size_t)h * HD + z) * NCTX + k] = f2b(acc[nf][r]);
      }
    }
  }
}

// K-proj (blocks [0,1024)) + Q-proj (blocks [1024,1536)) in one dispatch.
__global__ __launch_bounds__(256) void proj_kq(
    const u16* __restrict__ ctxb, const u16* __restrict__ wkb,
    const u16* __restrict__ tgtb, const u16* __restrict__ wqb,
    u16* __restrict__ Kbf, u16* __restrict__ Ktb, float* __restrict__ Qf) {
  __shared__ __align__(16) u16 sB[2][4096];
  if (blockIdx.x < (NCTX / 64) * (DMODEL / 64))
    gemm_body<1>(ctxb, wkb, nullptr, Kbf, Ktb, NCTX, DMODEL, DMODEL,
                 blockIdx.x, threadIdx.x, &sB[0][0]);
  else
    gemm_body<0>(tgtb, wqb, Qf, nullptr, nullptr, NTGT, DMODEL, DMODEL,
                 blockIdx.x - (NCTX / 64) * (DMODEL / 64), threadIdx.x, &sB[0][0]);
}

__global__ __launch_bounds__(256) void gemm_c(
    const u16* __restrict__ A, const u16* __restrict__ B, float* __restrict__ Cf,
    int M, int N, int Kd) {
  __shared__ __align__(16) u16 sB[2][4096];
  gemm_body<0>(A, B, Cf, nullptr, nullptr, M, N, Kd, blockIdx.x, threadIdx.x, &sB[0][0]);
}

// ---------------- 5-step energy attention, 8-wave / 128-k tiles ----------------
// Round-19 structure + raw v_exp_f32 (skips OCML denorm fixup; args bounded).
__global__ __launch_bounds__(512, 4) void attn5(
    const u16* __restrict__ Kbf,   // [NH][NCTX][HD], pre-scaled by beta*log2e
    const u16* __restrict__ Ktb,   // [NH][HD][NCTX]
    const float* __restrict__ Qf,  // [NTGT][DMODEL]
    u16* __restrict__ Qob) {       // [NTGT][DMODEL] bf16
  __shared__ __align__(16) u16 sTu[32768];   // 64KB: 2x32KB tile buffers
  __shared__ float lb[8][32];                // 1KB: per-wave row-sum partials

  const int bid = blockIdx.x;
  const int h  = ((bid & 7) << 1) | ((bid >> 3) & 1);
  const int qt = bid >> 4;
  const int w = threadIdx.x >> 6, l = threadIdx.x & 63;
  const int ln = l & 31, hi = l >> 5;
  const int qh = w & 1, kq = w >> 1;
  const int q0w = qt * 64 + qh * 32;

  const u16* Kh  = Kbf + (size_t)h * NCTX * HD;
  const u16* Kth = Ktb + (size_t)h * HD * NCTX;

  auto STAGE = [&](int b, int t) {
#pragma unroll
    for (int i = 0; i < 2; ++i) {
      const u16* src = Kh + (size_t)(t * 128 + w * 16 + i * 8 + (l >> 3)) * HD
                          + (((l & 7) ^ (l >> 3) ^ ((w * 2 + i) & 7)) << 3);
      __builtin_amdgcn_global_load_lds((g_u32*)src,
          (lds_u32*)(sTu + b * 16384 + (w * 16 + i * 8) * 64), 16, 0, 0);
    }
#pragma unroll
    for (int i = 0; i < 2; ++i) {
      const u16* src = Kth + (size_t)(w * 8 + i * 4 + (l >> 4)) * NCTX + t * 128
                           + (((l & 15) ^ ((w * 8 + i * 4 + (l >> 4)) & 15)) << 3);
      __builtin_amdgcn_global_load_lds((g_u32*)src,
          (lds_u32*)(sTu + b * 16384 + 8192 + (w * 8 + i * 4) * 128), 16, 0, 0);
    }
  };

  // ---- Q B-frags: lane q=ln, z = zc*16 + 8*hi + e ----
  short8 qfrag[4];
  {
    const float* qp = Qf + (size_t)(q0w + ln) * DMODEL + h * HD + hi * 8;
#pragma unroll
    for (int zc = 0; zc < 4; ++zc) {
      float4 f0 = *(const float4*)(qp + zc * 16);
      float4 f1 = *(const float4*)(qp + zc * 16 + 4);
      union { short8 s; uint32_t u[4]; } t;
      t.u[0] = pk2(f0.x, f0.y); t.u[1] = pk2(f0.z, f0.w);
      t.u[2] = pk2(f1.x, f1.y); t.u[3] = pk2(f1.z, f1.w);
      qfrag[zc] = t.s;
    }
  }
  // ---- distributed q-state: rows qq = i + 8*kq + 4*hi, cols ln / 32+ln ----
  float qst0[4], qst1[4];
#pragma unroll
  for (int i = 0; i < 4; ++i) {
    const int qq = i + 8 * kq + 4 * hi;
    const float* qp = Qf + (size_t)(q0w + qq) * DMODEL + h * HD;
    qst0[i] = qp[ln];
    qst1[i] = qp[32 + ln];
  }

  STAGE(0, 0);

  for (int step = 0; step < 5; ++step) {
    f32x16 acc0 = {}, acc1 = {};
    float2 lrow2 = make_float2(0.f, 0.f);

#pragma unroll 2
    for (int t = 0; t < 32; ++t) {
      const int buf = t & 1;
      asm volatile("s_waitcnt vmcnt(0)" ::: "memory");  // own tile-t loads done
      __builtin_amdgcn_s_barrier();                     // everyone's tile-t done
      if (t < 31) STAGE(buf ^ 1, t + 1);                // prefetch stays in flight
      const u16* tb = sTu + buf * 16384;

      // ---- St = K_strip * Q^T (k rows kq*32+ln, q cols = lanes) ----
      f32x16 st = {};
      __builtin_amdgcn_s_setprio(1);
#pragma unroll
      for (int zc = 0; zc < 4; ++zc) {
        const int b7 = (zc * 2 + hi) ^ (ln & 7) ^ ((kq * 4 + (ln >> 3)) & 7);
        short8 kf = *(const short8*)(tb + (kq * 32 + ln) * 64 + (b7 << 3));
        st = __builtin_amdgcn_mfma_f32_32x32x16_bf16(kf, qfrag[zc], st, 0, 0, 0);
      }
      __builtin_amdgcn_s_setprio(0);
      // ---- P = exp2(St); pack via cvt_pk + permlane32_swap; PV ----
      const u16* kt = tb + 8192;
#pragma unroll
      for (int kc = 0; kc < 2; ++kc) {
        float p0 = ex2(st[8 * kc + 0]), p1 = ex2(st[8 * kc + 1]);
        float p2 = ex2(st[8 * kc + 2]), p3 = ex2(st[8 * kc + 3]);
        float p4 = ex2(st[8 * kc + 4]), p5 = ex2(st[8 * kc + 5]);
        float p6 = ex2(st[8 * kc + 6]), p7 = ex2(st[8 * kc + 7]);
        float2 s01 = make_float2(p0 + p4, p1 + p5);
        float2 s23 = make_float2(p2 + p6, p3 + p7);
        lrow2.x += s01.x + s23.x;
        lrow2.y += s01.y + s23.y;
        uint32_t a0 = pk2(p0, p1), a1 = pk2(p2, p3);
        uint32_t b0 = pk2(p4, p5), b1 = pk2(p6, p7);
        asm("v_permlane32_swap_b32 %0, %1" : "+v"(a0), "+v"(b0));
        asm("v_permlane32_swap_b32 %0, %1" : "+v"(a1), "+v"(b1));
        union { short8 s; uint32_t u[4]; } pa;
        pa.u[0] = a0; pa.u[1] = a1; pa.u[2] = b0; pa.u[3] = b1;
        const int b16 = (kq * 4 + kc * 2 + hi) ^ (ln & 15);
        short8 v0 = *(const short8*)(kt + ln * 128 + (b16 << 3));
        short8 v1 = *(const short8*)(kt + (32 + ln) * 128 + (b16 << 3));
        __builtin_amdgcn_s_setprio(1);
        acc0 = __builtin_amdgcn_mfma_f32_32x32x16_bf16(pa.s, v0, acc0, 0, 0, 0);
        acc1 = __builtin_amdgcn_mfma_f32_32x32x16_bf16(pa.s, v1, acc1, 0, 0, 0);
        __builtin_amdgcn_s_setprio(0);
      }
    }

    __syncthreads();                       // all compute done; sTu free
    float lrow = lrow2.x + lrow2.y;
    lrow += __shfl_xor(lrow, 32);

    // ---- symmetric dump: all 8 waves write their partials ----
    float* md = (float*)sTu;               // 8 regions x 8KB = 64KB
    float* my = md + (kq * 2 + qh) * 2048;
#pragma unroll
    for (int rr = 0; rr < 16; ++rr) {
      my[rr * 64 + l] = acc0[rr];
      my[(rr + 16) * 64 + l] = acc1[rr];
    }
    if (hi == 0) lb[kq * 2 + qh][ln] = lrow;
    __syncthreads();

    // ---- distributed merge: wave (kq,qh) handles rr in [4kq, 4kq+4) ----
#pragma unroll
    for (int i = 0; i < 4; ++i) {
      const int rr = 4 * kq + i;
      const int qq = i + 8 * kq + 4 * hi;
      const float o0 = md[qh * 2048 + rr * 64 + l] + md[(2 + qh) * 2048 + rr * 64 + l]
                     + md[(4 + qh) * 2048 + rr * 64 + l] + md[(6 + qh) * 2048 + rr * 64 + l];
      const float o1 = md[qh * 2048 + (rr + 16) * 64 + l] + md[(2 + qh) * 2048 + (rr + 16) * 64 + l]
                     + md[(4 + qh) * 2048 + (rr + 16) * 64 + l] + md[(6 + qh) * 2048 + (rr + 16) * 64 + l];
      const float lt = lb[qh][qq] + lb[2 + qh][qq] + lb[4 + qh][qq] + lb[6 + qh][qq];
      const float sc = 0.1f / lt;
      qst0[i] += o0 * sc;
      qst1[i] += o1 * sc;
    }

    if (step < 4) {
      __syncthreads();                     // all dump reads done; region 6 free
      u16* qsm = sTu + 24576 + qh * 2048;  // bytes [48K,56K), overlays region 6
#pragma unroll
      for (int i = 0; i < 4; ++i) {
        const int qq = i + 8 * kq + 4 * hi;
        qsm[qq * 64 + ((((ln >> 3)) ^ (qq & 7)) << 3) + (ln & 7)] = f2b(qst0[i]);
        qsm[qq * 64 + ((((ln >> 3) + 4) ^ (qq & 7)) << 3) + (ln & 7)] = f2b(qst1[i]);
      }
      __syncthreads();                     // qs16 visible to all waves
      const u16* qsr = sTu + 24576 + qh * 2048;
#pragma unroll
      for (int zc = 0; zc < 4; ++zc)
        qfrag[zc] = *(const short8*)(qsr + ln * 64 + (((zc * 2 + hi) ^ (ln & 7)) << 3));
      STAGE(0, 0);                         // writes bytes [0, 32K), no overlap
    } else {
#pragma unroll
      for (int i = 0; i < 4; ++i) {
        const int qq = i + 8 * kq + 4 * hi;
        const size_t base = (size_t)(q0w + qq) * DMODEL + h * HD;
        Qob[base + ln] = f2b(qst0[i]);
        Qob[base + 32 + ln] = f2b(qst1[i]);
      }
    }
  }
}

extern "C" void kernel_launch(void* const* d_in, const int* in_sizes, int n_in,
                              void* d_out, int out_size, void* d_ws, size_t ws_size,
                              hipStream_t stream) {
  const float* ctx = (const float*)d_in[0];
  const float* tgt = (const float*)d_in[1];
  const float* Wq  = (const float*)d_in[2];
  const float* Wk  = (const float*)d_in[3];
  const float* Wo  = (const float*)d_in[4];

  uint8_t* wp = (uint8_t*)d_ws;
  u16* ctxb = (u16*)wp; wp += (size_t)NCTX * DMODEL * 2;
  u16* tgtb = (u16*)wp; wp += (size_t)NTGT * DMODEL * 2;
  u16* wqb  = (u16*)wp; wp += (size_t)DMODEL * DMODEL * 2;
  u16* wkb  = (u16*)wp; wp += (size_t)DMODEL * DMODEL * 2;
  u16* wob  = (u16*)wp; wp += (size_t)DMODEL * DMODEL * 2;
  u16* Kbf  = (u16*)wp; wp += (size_t)NH * NCTX * HD * 2;
  u16* Ktb  = (u16*)wp; wp += (size_t)NH * HD * NCTX * 2;
  float* Qf = (float*)wp; wp += (size_t)NTGT * DMODEL * 4;
  u16* Qob  = (u16*)wp; wp += (size_t)NTGT * DMODEL * 2;

  // 1 launch: all five f32->bf16 conversions (counts in float4 units)
  hipLaunchKernelGGL(cvt_fused, dim3(2048), dim3(256), 0, stream,
                     ctx, ctxb, (int)((size_t)NCTX * DMODEL / 4),
                     tgt, tgtb, (int)((size_t)NTGT * DMODEL / 4),
                     Wq, wqb, (int)((size_t)DMODEL * DMODEL / 4),
                     Wk, wkb, (int)((size_t)DMODEL * DMODEL / 4),
                     Wo, wob, (int)((size_t)DMODEL * DMODEL / 4));
  // 1 launch: K projection (1024 blocks) + Q projection (512 blocks)
  hipLaunchKernelGGL(proj_kq, dim3((NCTX / 64) * (DMODEL / 64) + (NTGT / 64) * (DMODEL / 64)),
                     dim3(256), 0, stream, ctxb, wkb, tgtb, wqb, Kbf, Ktb, Qf);
  // 5-step energy attention
  hipLaunchKernelGGL(attn5, dim3(512), dim3(512), 0, stream, Kbf, Ktb, Qf, Qob);
  // Output projection: Qob x Wo^T -> d_out (f32)
  hipLaunchKernelGGL(gemm_c, dim3((NTGT / 64) * (DMODEL / 64)), dim3(256), 0, stream,
                     Qob, wob, (float*)d_out, NTGT, DMODEL, DMODEL);
}